// Round 1
// baseline (19122.731 us; speedup 1.0000x reference)
//
#include <hip/hip_runtime.h>
#include <hip/hip_bf16.h>
#include <cmath>

// All float tensors f32 (reference: jnp.float32). Output f32 [64].
// B=32, S=64, T=64, E=512, H=512, 4H=2048, V=32000

__device__ __forceinline__ float sigf(float x){ return 1.0f/(1.0f+__expf(-x)); }
__device__ __forceinline__ short f2bf(float x){
    unsigned u = __builtin_bit_cast(unsigned, x);
    u += 0x7fff + ((u >> 16) & 1);
    return (short)(u >> 16);
}

typedef __attribute__((ext_vector_type(8))) short short8;   // 8 bf16 (4 VGPR)
typedef __attribute__((ext_vector_type(4))) float float4v;  // 4 f32 acc

// ---------------- workspace (d_ws) layout, proven <=22.5MB ----------------
constexpr long o_senc   = 0;                     // [B][S][1024]
constexpr long o_satt   = o_senc + 32L*64*1024;  // [B][S][512]
constexpr long o_aves   = o_satt + 32L*64*512;   // [T*B][512] f32
constexpr long o_hF     = o_aves + 64L*32*512;   // zero-block start
constexpr long o_cF     = o_hF + 32L*512;
constexpr long o_hB     = o_cF + 32L*512;
constexpr long o_cB     = o_hB + 32L*512;
constexpr long o_sumexp = o_cB + 32L*512;        // 2048 (zero block = 67584 floats)
constexpr long o_gold   = o_sumexp + 2048;
constexpr long o_ccat   = o_gold + 2048;         // [32][1024]
constexpr long o_dech   = o_ccat + 32L*1024;
constexpr long o_decc   = o_dech + 32L*512;
constexpr long o_att    = o_decc + 32L*512;      // attG [32][512]
constexpr long o_ctx    = o_att + 32L*512;       // [32][1024]

// ---------------- static device buffers (independent of ws_size) ----------------
__device__ __align__(16) float g_X[3][2048L*2048];     // Xf, Xb, Yg (raw x-part gates)
__device__ __align__(16) short g_Wread_bf[32000L*512];
__device__ __align__(16) short g_bfA[2][2048L*512];    // srcx_bf, tgty_bf
__device__ __align__(16) short g_bfW[3][2048L*512];    // WihF_bf, WihB_bf, dWihY_bf
__device__ __align__(16) short g_aves_bf[2048L*512];

// ---------------- grid barrier (persistent kernels) ----------------
// Monotonic across launches and graph replays: never reset.
// Invariant at rest: g_cnt == 256 * g_rel  (both coop kernels use 256 blocks).
__device__ unsigned long long g_cnt = 0ull;
__device__ unsigned long long g_rel = 0ull;

__device__ __forceinline__ void grid_sync(unsigned long long epoch, unsigned nblk){
    __threadfence();          // release this thread's prior writes (agent scope)
    __syncthreads();          // all threads of block fenced before arrival
    if (threadIdx.x == 0){
        unsigned long long old = __hip_atomic_fetch_add(&g_cnt, 1ull,
                                    __ATOMIC_ACQ_REL, __HIP_MEMORY_SCOPE_AGENT);
        if (old == epoch*(unsigned long long)nblk - 1ull){
            __hip_atomic_store(&g_rel, epoch, __ATOMIC_RELEASE, __HIP_MEMORY_SCOPE_AGENT);
        } else {
            while (__hip_atomic_load(&g_rel, __ATOMIC_ACQUIRE, __HIP_MEMORY_SCOPE_AGENT) < epoch)
                __builtin_amdgcn_s_sleep(2);
        }
    }
    __syncthreads();
    __threadfence();          // acquire side: invalidate stale L1 for everyone
}

// ---------------- utility ----------------
__global__ void k_zero(float* p, int n){
    int i = blockIdx.x*256 + threadIdx.x;
    if (i < n) p[i] = 0.f;
}

// f32 [rows][ldin] (first 512 cols) -> bf16 [rows][512]
__global__ void k_cvt(const float* __restrict__ in, short* __restrict__ out, int ldin){
    long idx = (long)blockIdx.x*256 + threadIdx.x;
    long r = idx >> 9; int c = idx & 511;
    out[idx] = f2bf(in[r*ldin + c]);
}

// token gather -> bf16 rows. mode 0: src flat-reshape; mode 1: tgt transpose
__global__ void k_gather_bf(const float* __restrict__ emb, const int* __restrict__ tok,
                            short* __restrict__ out, int mode){
    long idx = (long)blockIdx.x*256 + threadIdx.x;   // 2048*512
    int m = idx >> 9, e = idx & 511;
    int ti = mode ? ((m & 31)*64 + (m >> 5)) : m;
    out[idx] = f2bf(emb[(long)tok[ti]*512 + e]);
}

// ---------------- MFMA bf16 GEMM: C[m,n] = sum_k A[m,k]*B[n,k], K=512 ----------------
// STORE=1: store f32 C (ldc=N). STORE=0: atomicAdd(sumexp[m], sum_n exp(C[m,n])).
template<int STORE>
__global__ __launch_bounds__(256)
void k_mfma_gemm(const short* __restrict__ A, const short* __restrict__ B,
                 float* __restrict__ C, int ldc){
    __shared__ short As[128][72];
    __shared__ short Bs[128][72];
    int tid = threadIdx.x, l = tid & 63, w = tid >> 6;
    int wm = w >> 1, wn = w & 1;
    long m0 = (long)blockIdx.x * 128, n0 = (long)blockIdx.y * 128;
    float4v acc[4][4];
    #pragma unroll
    for (int a=0;a<4;++a)
        #pragma unroll
        for (int b=0;b<4;++b)
            #pragma unroll
            for (int e=0;e<4;++e) acc[a][b][e] = 0.f;

    for (int kb = 0; kb < 8; ++kb){
        #pragma unroll
        for (int i = tid; i < 1024; i += 256){
            int r = i >> 3, c = i & 7;
            *(uint4*)&As[r][c*8] = *(const uint4*)(A + (m0+r)*512 + kb*64 + c*8);
            *(uint4*)&Bs[r][c*8] = *(const uint4*)(B + (n0+r)*512 + kb*64 + c*8);
        }
        __syncthreads();
        #pragma unroll
        for (int ks = 0; ks < 2; ++ks){
            short8 af[4], bf[4];
            #pragma unroll
            for (int tm=0;tm<4;++tm)
                af[tm] = *(const short8*)&As[wm*64 + tm*16 + (l&15)][ks*32 + (l>>4)*8];
            #pragma unroll
            for (int tn=0;tn<4;++tn)
                bf[tn] = *(const short8*)&Bs[wn*64 + tn*16 + (l&15)][ks*32 + (l>>4)*8];
            #pragma unroll
            for (int tm=0;tm<4;++tm)
                #pragma unroll
                for (int tn=0;tn<4;++tn)
                    acc[tm][tn] = __builtin_amdgcn_mfma_f32_16x16x32_bf16(
                        af[tm], bf[tn], acc[tm][tn], 0, 0, 0);
        }
        __syncthreads();
    }

    int q = l >> 4;  // quad group
    if (STORE){
        #pragma unroll
        for (int tm=0;tm<4;++tm)
            #pragma unroll
            for (int r=0;r<4;++r){
                long m = m0 + wm*64 + tm*16 + q*4 + r;
                #pragma unroll
                for (int tn=0;tn<4;++tn)
                    C[m*ldc + n0 + wn*64 + tn*16 + (l&15)] = acc[tm][tn][r];
            }
    } else {
        #pragma unroll
        for (int tm=0;tm<4;++tm)
            #pragma unroll
            for (int r=0;r<4;++r){
                float s = 0.f;
                #pragma unroll
                for (int tn=0;tn<4;++tn) s += __expf(acc[tm][tn][r]);
                s += __shfl_xor(s, 1); s += __shfl_xor(s, 2);
                s += __shfl_xor(s, 4); s += __shfl_xor(s, 8);
                if ((l & 15) == 0)
                    atomicAdd(&C[m0 + wm*64 + tm*16 + q*4 + r], s);
            }
    }
}

// ---------------- persistent encoder ----------------
// 256 blocks x 256 threads, 1 block/CU (LDS ~101KB). dir = bid>>7, j-group of 4.
// Whh slice LDS-resident across all 64 steps; c-state register-resident.
// 1 grid-sync per step.
__global__ __launch_bounds__(256, 1)
void k_encoder(const float* __restrict__ WhhF, const float* __restrict__ WhhB,
               const float* __restrict__ bF, const float* __restrict__ bB,
               const int* __restrict__ lens,
               float* __restrict__ hF, float* __restrict__ cF,
               float* __restrict__ hB, float* __restrict__ cB,
               float* __restrict__ senc)
{
    __shared__ float WS[16][516];   // 16 gate-rows x 512 (pad 4)
    __shared__ float xS[32][516];   // h stage [32][512] (pad 4)
    __shared__ float gS[32][16];    // gate partial exchange

    const int bid = blockIdx.x, tid = threadIdx.x;
    const int dir = bid >> 7, jg = bid & 127;
    const int j0 = jg * 4;
    const float* Whh  = dir ? WhhB : WhhF;
    const float* bias = dir ? bB : bF;
    const float* X = g_X[dir];
    float* hPtr = dir ? hB : hF;

    // stage W once: row nn -> gate n = (nn>>2)*512 + j0 + (nn&3)
    for (int i = tid; i < 2048; i += 256){
        int nn = i >> 7, c4 = i & 127;
        int n = (nn >> 2)*512 + j0 + (nn & 3);
        *(float4*)&WS[nn][c4*4] = *(const float4*)(Whh + (long)n*512 + c4*4);
    }

    const int nn = tid & 15, b2 = tid >> 4;        // compute map: 2 outputs (b2, b2+16)
    const int cb = tid >> 2, cjj = tid & 3;        // cell map (tid<128)
    const int len_b = lens[cb & 31];
    float c_reg = 0.f, h_reg = 0.f;

    unsigned long long ep = __hip_atomic_load(&g_rel, __ATOMIC_RELAXED, __HIP_MEMORY_SCOPE_AGENT);
    const unsigned nblk = gridDim.x;

    for (int s = 0; s < 64; ++s){
        if (s){
            ep++; grid_sync(ep, nblk);
            for (int i = tid; i < 4096; i += 256){   // stage h [32][512]
                int r = i >> 7, c4 = i & 127;
                *(float4*)&xS[r][c4*4] = *(const float4*)(hPtr + r*512 + c4*4);
            }
        }
        __syncthreads();
        float p[4] = {0.f,0.f,0.f,0.f}, q[4] = {0.f,0.f,0.f,0.f};
        if (s){
            const float* wr = &WS[nn][0];
            const float* xa = &xS[b2][0];
            const float* xb = &xS[b2 + 16][0];
            #pragma unroll 2
            for (int k = 0; k < 512; k += 16){
                #pragma unroll
                for (int u = 0; u < 4; ++u){
                    float4 w = *(const float4*)(wr + k + u*4);
                    float4 a = *(const float4*)(xa + k + u*4);
                    float4 b = *(const float4*)(xb + k + u*4);
                    p[u] += w.x*a.x + w.y*a.y + w.z*a.z + w.w*a.w;
                    q[u] += w.x*b.x + w.y*b.y + w.z*b.z + w.w*b.w;
                }
            }
        }
        gS[b2][nn]    = p[0]+p[1]+p[2]+p[3];
        gS[b2+16][nn] = q[0]+q[1]+q[2]+q[3];
        __syncthreads();
        if (tid < 128){
            int sd = dir ? 63 - s : s;
            int j = j0 + cjj;
            const float* xr = X + ((long)(sd*32 + cb))*2048;
            float g0 = gS[cb][cjj]      + xr[j]      + bias[j];
            float g1 = gS[cb][4 + cjj]  + xr[512+j]  + bias[512+j];
            float g2 = gS[cb][8 + cjj]  + xr[1024+j] + bias[1024+j];
            float g3 = gS[cb][12 + cjj] + xr[1536+j] + bias[1536+j];
            float cn = sigf(g1)*c_reg + sigf(g0)*tanhf(g2);
            float hn = sigf(g3)*tanhf(cn);
            bool valid = sd < len_b;
            c_reg = valid ? cn : c_reg;
            h_reg = valid ? hn : h_reg;
            hPtr[cb*512 + j] = h_reg;
            senc[((long)(cb*64 + sd))*1024 + dir*512 + j] = valid ? hn : 0.f;
        }
    }
    if (tid < 128){
        float* cOut = dir ? cB : cF;
        cOut[cb*512 + j0 + cjj] = c_reg;
    }
}

// ---------------- persistent decoder ----------------
// 256 blocks x 256 threads, 1 block/CU (LDS ~127KB). 3 grid-syncs per step.
// Phase A: gates (Whh + Wih-att slices LDS-resident), cell with register c.
// Phase B: scores/softmax/ctx (b = bid>>3, col-slice = bid&7).
// Phase C: attvec (bid<128, 4 Wavec rows LDS-resident), writes att/aves.
__global__ __launch_bounds__(256, 1)
void k_decoder(const float* __restrict__ dWhh, const float* __restrict__ dWih,
               const float* __restrict__ db, const float* __restrict__ Wv,
               const float* __restrict__ satt, const float* __restrict__ senc,
               const int* __restrict__ lens,
               float* __restrict__ dech, const float* __restrict__ decc,
               float* __restrict__ attG, float* __restrict__ ctxG,
               float* __restrict__ aves)
{
    __shared__ float xS[32][516];     // stage [32][512] (pad 4)
    __shared__ float WdS[8][1028];    // 8 gate-rows x [Whh(512) | Wih-att(512)]
    __shared__ float WvS[4][1540];    // 4 Wavec rows x 1536 (bid<128)
    __shared__ float gS[32][8];
    __shared__ float scoreQ[64][5];
    __shared__ float alphaS[64];
    __shared__ float ctxP[2][128];

    const int bid = blockIdx.x, tid = threadIdx.x;
    const float* Yg = g_X[2];

    {   // stage decoder gate weights once
        int j0 = bid*2;
        for (int i = tid; i < 2048; i += 256){
            int nn = i >> 8, c4 = i & 255;
            int n = (nn >> 1)*512 + j0 + (nn & 1);
            float4 v;
            if (c4 < 128) v = *(const float4*)(dWhh + (long)n*512  + c4*4);
            else          v = *(const float4*)(dWih + (long)n*1024 + 512 + (c4-128)*4);
            *(float4*)&WdS[nn][c4*4] = v;
        }
        if (bid < 128){
            for (int i = tid; i < 1536; i += 256){
                int r = i / 384, c4 = i % 384;
                *(float4*)&WvS[r][c4*4] = *(const float4*)(Wv + (long)(bid*4+r)*1536 + c4*4);
            }
        }
    }

    // cell state in registers (tid<64): b = tid>>1, j = bid*2 + (tid&1)
    float c_reg = 0.f;
    if (tid < 64) c_reg = decc[(tid>>1)*512 + bid*2 + (tid&1)];

    const int nnA = tid & 7, bA = tid >> 3;   // phase A map: 1 output/thread
    unsigned long long ep = __hip_atomic_load(&g_rel, __ATOMIC_RELAXED, __HIP_MEMORY_SCOPE_AGENT);
    const unsigned nblk = gridDim.x;

    for (int t = 0; t < 64; ++t){
        if (t){ ep++; grid_sync(ep, nblk); }

        // ---------- phase A: gates + cell ----------
        for (int i = tid; i < 4096; i += 256){   // stage h
            int r = i >> 7, c4 = i & 127;
            *(float4*)&xS[r][c4*4] = *(const float4*)(dech + r*512 + c4*4);
        }
        __syncthreads();
        float p[4] = {0.f,0.f,0.f,0.f};
        {
            const float* wr = &WdS[nnA][0];
            const float* xr = &xS[bA][0];
            #pragma unroll 2
            for (int k = 0; k < 512; k += 16){
                #pragma unroll
                for (int u = 0; u < 4; ++u){
                    float4 w = *(const float4*)(wr + k + u*4);
                    float4 a = *(const float4*)(xr + k + u*4);
                    p[u] += w.x*a.x + w.y*a.y + w.z*a.z + w.w*a.w;
                }
            }
        }
        if (t){   // att-part (att0 == 0 at t==0)
            __syncthreads();
            for (int i = tid; i < 4096; i += 256){
                int r = i >> 7, c4 = i & 127;
                *(float4*)&xS[r][c4*4] = *(const float4*)(attG + r*512 + c4*4);
            }
            __syncthreads();
            const float* wr = &WdS[nnA][512];
            const float* xr = &xS[bA][0];
            #pragma unroll 2
            for (int k = 0; k < 512; k += 16){
                #pragma unroll
                for (int u = 0; u < 4; ++u){
                    float4 w = *(const float4*)(wr + k + u*4);
                    float4 a = *(const float4*)(xr + k + u*4);
                    p[u] += w.x*a.x + w.y*a.y + w.z*a.z + w.w*a.w;
                }
            }
        }
        gS[bA][nnA] = p[0]+p[1]+p[2]+p[3];
        __syncthreads();
        if (tid < 64){
            int b = tid >> 1, jj = tid & 1, j = bid*2 + jj;
            const float* yr = Yg + ((long)t*32 + b)*2048;
            float g0 = gS[b][0 + jj] + yr[j]      + db[j];
            float g1 = gS[b][2 + jj] + yr[512+j]  + db[512+j];
            float g2 = gS[b][4 + jj] + yr[1024+j] + db[1024+j];
            float g3 = gS[b][6 + jj] + yr[1536+j] + db[1536+j];
            float cn = sigf(g1)*c_reg + sigf(g0)*tanhf(g2);
            float hn = sigf(g3)*tanhf(cn);
            c_reg = cn;
            dech[b*512 + j] = hn;
        }
        ep++; grid_sync(ep, nblk);

        // ---------- phase B: scores -> softmax -> ctx slice ----------
        {
            int bb = bid >> 3, cs = bid & 7;
            float* hBS = &xS[0][0];   // flat 512 floats
            for (int i = tid; i < 128; i += 256)
                *(float4*)&hBS[i*4] = *(const float4*)(dech + bb*512 + i*4);
            __syncthreads();
            {
                int ss = tid >> 2, qq = tid & 3;
                const float* sar = satt + ((long)(bb*64 + ss))*512 + qq*128;
                const float* hr = hBS + qq*128;
                float u[4] = {0.f,0.f,0.f,0.f};
                #pragma unroll 2
                for (int k = 0; k < 128; k += 16){
                    #pragma unroll
                    for (int u4 = 0; u4 < 4; ++u4){
                        float4 a = *(const float4*)(sar + k + u4*4);
                        float4 h = *(const float4*)(hr  + k + u4*4);
                        u[u4] += a.x*h.x + a.y*h.y + a.z*h.z + a.w*h.w;
                    }
                }
                scoreQ[ss][qq] = u[0]+u[1]+u[2]+u[3];
            }
            __syncthreads();
            if (tid < 64){
                float sc = scoreQ[tid][0]+scoreQ[tid][1]+scoreQ[tid][2]+scoreQ[tid][3];
                if (tid >= lens[bb]) sc = -INFINITY;
                float mx = sc;
                #pragma unroll
                for (int o=32;o>0;o>>=1) mx = fmaxf(mx, __shfl_xor(mx, o));
                float e = (sc == -INFINITY) ? 0.f : __expf(sc - mx);
                float sm = e;
                #pragma unroll
                for (int o=32;o>0;o>>=1) sm += __shfl_xor(sm, o);
                alphaS[tid] = e / fmaxf(sm, 1e-30f);
            }
            __syncthreads();
            {
                int cc = tid & 127, sh = tid >> 7;
                const float* sb = senc + ((long)bb*64 + sh*32)*1024 + cs*128 + cc;
                float a0 = 0.f, a1 = 0.f;
                for (int s2 = 0; s2 < 32; s2 += 2){
                    a0 += alphaS[sh*32 + s2]     * sb[(long)s2*1024];
                    a1 += alphaS[sh*32 + s2 + 1] * sb[(long)(s2+1)*1024];
                }
                ctxP[sh][cc] = a0 + a1;
            }
            __syncthreads();
            if (tid < 128) ctxG[(bid>>3)*1024 + (bid&7)*128 + tid] = ctxP[0][tid] + ctxP[1][tid];
        }
        ep++; grid_sync(ep, nblk);

        // ---------- phase C: attvec -> att, aves ----------
        if (bid < 128){
            int b3 = tid >> 3, nv = (tid >> 1) & 3, kq = tid & 1;
            float q[4] = {0.f,0.f,0.f,0.f};
            for (int ch = 0; ch < 3; ++ch){
                for (int i = tid; i < 4096; i += 256){
                    int r = i >> 7, c4 = i & 127;
                    float4 v;
                    if (ch == 0) v = *(const float4*)(dech + r*512 + c4*4);
                    else         v = *(const float4*)(ctxG + (long)r*1024 + (ch-1)*512 + c4*4);
                    *(float4*)&xS[r][c4*4] = v;
                }
                __syncthreads();
                const float* xr = &xS[b3][kq*256];
                const float* wr = &WvS[nv][ch*512 + kq*256];
                #pragma unroll 2
                for (int k = 0; k < 256; k += 16){
                    #pragma unroll
                    for (int u = 0; u < 4; ++u){
                        float4 w = *(const float4*)(wr + k + u*4);
                        float4 a = *(const float4*)(xr + k + u*4);
                        q[u] += w.x*a.x + w.y*a.y + w.z*a.z + w.w*a.w;
                    }
                }
                __syncthreads();
            }
            float acc = q[0]+q[1]+q[2]+q[3];
            acc += __shfl_xor(acc, 1);
            if (kq == 0){
                float v = tanhf(acc);
                int n = bid*4 + nv;
                attG[b3*512 + n] = v;
                long m = (long)t*32 + b3;
                aves[m*512 + n] = v;
                g_aves_bf[m*512 + n] = f2bf(v);
            }
        }
    }
}

__global__ void k_ccat(const float* __restrict__ cF, const float* __restrict__ cB,
                       float* __restrict__ ccat){
    int idx = blockIdx.x*256 + threadIdx.x;   // 32*1024
    int b = idx >> 10, d = idx & 1023;
    ccat[idx] = (d < 512) ? cF[b*512+d] : cB[b*512+d-512];
}

// ---------------- generic f32 tiled GEMM (satt, init) ----------------
__global__ __launch_bounds__(256)
void k_gemm(const float* __restrict__ A, const float* __restrict__ W,
            const float* __restrict__ bias, float* __restrict__ C,
            int M, int K, int lda, int ldw, int ldc){
    __shared__ float As[16][65];
    __shared__ float Wt[16][65];
    int tid = threadIdx.x;
    int m0 = blockIdx.x * 64, n0 = blockIdx.y * 64;
    int ty = tid >> 4, tx = tid & 15;
    int lm = tid >> 2, lk = (tid & 3) * 4;
    float acc[4][4] = {};
    for (int kt = 0; kt < K; kt += 16){
        float4 av;
        if (m0 + lm < M) av = *(const float4*)(A + (long)(m0+lm)*lda + kt + lk);
        else av = make_float4(0.f,0.f,0.f,0.f);
        As[lk+0][lm]=av.x; As[lk+1][lm]=av.y; As[lk+2][lm]=av.z; As[lk+3][lm]=av.w;
        float4 wv = *(const float4*)(W + (long)(n0+lm)*ldw + kt + lk);
        Wt[lk+0][lm]=wv.x; Wt[lk+1][lm]=wv.y; Wt[lk+2][lm]=wv.z; Wt[lk+3][lm]=wv.w;
        __syncthreads();
        #pragma unroll
        for (int k = 0; k < 16; ++k){
            float a0=As[k][ty*4+0], a1=As[k][ty*4+1], a2=As[k][ty*4+2], a3=As[k][ty*4+3];
            float b0=Wt[k][tx*4+0], b1=Wt[k][tx*4+1], b2=Wt[k][tx*4+2], b3=Wt[k][tx*4+3];
            acc[0][0]+=a0*b0; acc[0][1]+=a0*b1; acc[0][2]+=a0*b2; acc[0][3]+=a0*b3;
            acc[1][0]+=a1*b0; acc[1][1]+=a1*b1; acc[1][2]+=a1*b2; acc[1][3]+=a1*b3;
            acc[2][0]+=a2*b0; acc[2][1]+=a2*b1; acc[2][2]+=a2*b2; acc[2][3]+=a2*b3;
            acc[3][0]+=a3*b0; acc[3][1]+=a3*b1; acc[3][2]+=a3*b2; acc[3][3]+=a3*b3;
        }
        __syncthreads();
    }
    #pragma unroll
    for (int i=0;i<4;++i){
        int m = m0 + ty*4 + i;
        if (m >= M) continue;
        #pragma unroll
        for (int j=0;j<4;++j){
            int n = n0 + tx*4 + j;
            float v = acc[i][j];
            if (bias) v += bias[n];
            C[(long)m*ldc + n] = v;
        }
    }
}

__global__ void k_dec_init(const float* __restrict__ decc0, float* dech){
    int idx = blockIdx.x*256 + threadIdx.x;   // 16384
    dech[idx] = tanhf(decc0[idx]);
}

// ---------------- gold + final ----------------
__global__ void k_gold(const float* __restrict__ aves, const float* __restrict__ Wr,
                       const int* __restrict__ tgt, float* __restrict__ gold){
    int wid = threadIdx.x >> 6, lane = threadIdx.x & 63;
    int m = blockIdx.x*4 + wid;   // m = t*32 + b
    int t = m >> 5, b = m & 31;
    int g = tgt[b*64 + t];
    const float* arow = aves + (long)m*512;
    const float* wrow = Wr + (long)g*512;
    float p = 0.f;
    for (int k=lane; k<512; k+=64) p += arow[k]*wrow[k];
    #pragma unroll
    for (int o=32;o>0;o>>=1) p += __shfl_xor(p, o);
    if (lane == 0) gold[m] = p;
}

__global__ void k_final(const float* __restrict__ gold, const float* __restrict__ sumexp,
                        const int* __restrict__ tgt, float* __restrict__ out){
    int t = threadIdx.x;
    float a = 0.f;
    for (int b=0;b<32;++b){
        int m = t*32 + b;
        float lp = gold[m] - logf(fmaxf(sumexp[m], 1e-30f));
        if (tgt[b*64 + t] != 0) a += lp;
    }
    out[t] = a;
}

// ---------------- launch ----------------
extern "C" void kernel_launch(void* const* d_in, const int* in_sizes, int n_in,
                              void* d_out, int out_size, void* d_ws, size_t ws_size,
                              hipStream_t stream){
    const int* src_tok   = (const int*)d_in[0];
    const int* tgt_tok   = (const int*)d_in[1];
    const int* lens      = (const int*)d_in[2];
    const float* src_emb = (const float*)d_in[3];
    const float* tgt_emb = (const float*)d_in[4];
    const float* eWihF   = (const float*)d_in[5];
    const float* eWhhF   = (const float*)d_in[6];
    const float* ebF     = (const float*)d_in[7];
    const float* eWihB   = (const float*)d_in[8];
    const float* eWhhB   = (const float*)d_in[9];
    const float* ebB     = (const float*)d_in[10];
    const float* dWih    = (const float*)d_in[11];
    const float* dWhh    = (const float*)d_in[12];
    const float* db      = (const float*)d_in[13];
    const float* Wasrc   = (const float*)d_in[14];
    const float* Wavec   = (const float*)d_in[15];
    const float* Wread   = (const float*)d_in[16];
    const float* Winit   = (const float*)d_in[17];
    const float* binit   = (const float*)d_in[18];
    float* ws  = (float*)d_ws;
    float* out = (float*)d_out;

    float* senc = ws + o_senc;  float* satt = ws + o_satt; float* aves = ws + o_aves;
    float* hF = ws + o_hF; float* cF = ws + o_cF; float* hB = ws + o_hB; float* cB = ws + o_cB;
    float* sumexp = ws + o_sumexp; float* gold = ws + o_gold;
    float* ccat = ws + o_ccat;
    float* dech = ws + o_dech; float* decc = ws + o_decc;
    float* attG = ws + o_att; float* ctxG = ws + o_ctx;

    // device-symbol pointers
    float* Xf; short *WreadBf, *srcxBf, *tgtyBf, *WihFbf, *WihBbf, *dWihYbf;
    hipGetSymbolAddress((void**)&Xf, HIP_SYMBOL(g_X));
    hipGetSymbolAddress((void**)&WreadBf, HIP_SYMBOL(g_Wread_bf));
    hipGetSymbolAddress((void**)&srcxBf, HIP_SYMBOL(g_bfA));
    hipGetSymbolAddress((void**)&WihFbf, HIP_SYMBOL(g_bfW));
    tgtyBf = srcxBf + 2048L*512;
    WihBbf = WihFbf + 2048L*512;
    dWihYbf = WihFbf + 2L*2048*512;
    float* Xb = Xf + 2048L*2048;
    float* Yg = Xf + 2L*2048*2048;
    (void)Xb; (void)Yg;

    // zero states + sumexp
    k_zero<<<264, 256, 0, stream>>>(hF, 67584);

    // bf16 conversions + gathers
    k_cvt<<<4096, 256, 0, stream>>>(eWihF, WihFbf, 512);
    k_cvt<<<4096, 256, 0, stream>>>(eWihB, WihBbf, 512);
    k_cvt<<<4096, 256, 0, stream>>>(dWih, dWihYbf, 1024);   // cols 0..511
    k_cvt<<<64000, 256, 0, stream>>>(Wread, WreadBf, 512);
    k_gather_bf<<<4096, 256, 0, stream>>>(src_emb, src_tok, srcxBf, 0);
    k_gather_bf<<<4096, 256, 0, stream>>>(tgt_emb, tgt_tok, tgtyBf, 1);

    // x-part precompute: Xf, Xb, Yg = emb x Wih^T (MFMA)
    k_mfma_gemm<1><<<dim3(16,16), 256, 0, stream>>>(srcxBf, WihFbf, Xf, 2048);
    k_mfma_gemm<1><<<dim3(16,16), 256, 0, stream>>>(srcxBf, WihBbf, Xf + 2048L*2048, 2048);
    k_mfma_gemm<1><<<dim3(16,16), 256, 0, stream>>>(tgtyBf, dWihYbf, Xf + 2L*2048*2048, 2048);

    // encoder recurrence: ONE persistent kernel (64 steps, 63 grid-syncs)
    k_encoder<<<256, 256, 0, stream>>>(eWhhF, eWhhB, ebF, ebB, lens, hF, cF, hB, cB, senc);

    // [c_f|c_b]; src_att; decoder init
    k_ccat<<<128, 256, 0, stream>>>(cF, cB, ccat);
    k_gemm<<<dim3(32,8), 256, 0, stream>>>(senc, Wasrc, nullptr, satt, 2048, 1024, 1024, 1024, 512);
    k_gemm<<<dim3(1,8), 256, 0, stream>>>(ccat, Winit, binit, decc, 32, 1024, 1024, 1024, 512);
    k_dec_init<<<64, 256, 0, stream>>>(decc, dech);

    // decoder recurrence: ONE persistent kernel (64 steps, 191 grid-syncs)
    k_decoder<<<256, 256, 0, stream>>>(dWhh, dWih, db, Wavec, satt, senc, lens,
                                       dech, decc, attG, ctxG, aves);

    // readout: MFMA bf16 GEMM with fused exp-sum; gold; final
    short* avesBf; hipGetSymbolAddress((void**)&avesBf, HIP_SYMBOL(g_aves_bf));
    k_mfma_gemm<0><<<dim3(16,250), 256, 0, stream>>>(avesBf, WreadBf, sumexp, 0);
    k_gold<<<512, 256, 0, stream>>>(aves, Wread, tgt_tok, gold);
    k_final<<<1, 64, 0, stream>>>(gold, sumexp, tgt_tok, out);
}

// Round 2
// 8993.871 us; speedup vs baseline: 2.1262x; 2.1262x over previous
//
#include <hip/hip_runtime.h>
#include <hip/hip_bf16.h>
#include <cmath>

// All float tensors f32 (reference: jnp.float32). Output f32 [64].
// B=32, S=64, T=64, E=512, H=512, 4H=2048, V=32000

__device__ __forceinline__ float sigf(float x){ return 1.0f/(1.0f+__expf(-x)); }
__device__ __forceinline__ short f2bf(float x){
    unsigned u = __builtin_bit_cast(unsigned, x);
    u += 0x7fff + ((u >> 16) & 1);
    return (short)(u >> 16);
}

typedef __attribute__((ext_vector_type(8))) short short8;   // 8 bf16 (4 VGPR)
typedef __attribute__((ext_vector_type(4))) float float4v;  // 4 f32 acc

// ---------------- workspace (d_ws) layout, proven <=22.5MB ----------------
constexpr long o_senc   = 0;                     // [B][S][1024]
constexpr long o_satt   = o_senc + 32L*64*1024;  // [B][S][512]
constexpr long o_aves   = o_satt + 32L*64*512;   // [T*B][512] f32
constexpr long o_hF     = o_aves + 64L*32*512;   // zero-block start
constexpr long o_cF     = o_hF + 32L*512;
constexpr long o_hB     = o_cF + 32L*512;
constexpr long o_cB     = o_hB + 32L*512;
constexpr long o_sumexp = o_cB + 32L*512;        // 2048 (zero block = 67584 floats)
constexpr long o_gold   = o_sumexp + 2048;
constexpr long o_ccat   = o_gold + 2048;         // [32][1024]
constexpr long o_dech   = o_ccat + 32L*1024;
constexpr long o_decc   = o_dech + 32L*512;
constexpr long o_att    = o_decc + 32L*512;      // attG [32][512]
constexpr long o_ctx    = o_att + 32L*512;       // [32][1024]

// ---------------- static device buffers (independent of ws_size) ----------------
__device__ __align__(16) float g_X[3][2048L*2048];     // Xf, Xb, Yg (raw x-part gates)
__device__ __align__(16) short g_Wread_bf[32000L*512];
__device__ __align__(16) short g_bfA[2][2048L*512];    // srcx_bf, tgty_bf
__device__ __align__(16) short g_bfW[3][2048L*512];    // WihF_bf, WihB_bf, dWihY_bf
__device__ __align__(16) short g_aves_bf[2048L*512];

// ---------------- grid barrier (persistent kernels) ----------------
// Two-level, monotonic-epoch, never reset (graph-replay safe).
// Arrival: per-block padded flag (parallel release stores, no RMW contention).
// Block 0 aggregates with 256 threads polling RELAXED, then releases g_rel.
// Workers poll g_rel RELAXED; exactly ONE acquire fence after observation.
__device__ __align__(128) unsigned long long g_arr[256][16];  // 128B stride/block
__device__ unsigned long long g_rel = 0ull;

__device__ __forceinline__ void gsync(unsigned long long ep){
    __syncthreads();   // all block threads' writes issued before arrival
    if (blockIdx.x == 0){
        int tid = threadIdx.x;
        if (tid > 0){   // thread t waits for block t's arrival flag
            while (__hip_atomic_load(&g_arr[tid][0], __ATOMIC_RELAXED,
                                     __HIP_MEMORY_SCOPE_AGENT) < ep)
                __builtin_amdgcn_s_sleep(1);
        }
        __syncthreads();
        __threadfence();   // acquire workers' data; order before release below
        if (tid == 0)
            __hip_atomic_store(&g_rel, ep, __ATOMIC_RELEASE, __HIP_MEMORY_SCOPE_AGENT);
    } else {
        if (threadIdx.x == 0){
            __hip_atomic_store(&g_arr[blockIdx.x][0], ep, __ATOMIC_RELEASE,
                               __HIP_MEMORY_SCOPE_AGENT);
            while (__hip_atomic_load(&g_rel, __ATOMIC_RELAXED,
                                     __HIP_MEMORY_SCOPE_AGENT) < ep)
                __builtin_amdgcn_s_sleep(1);
        }
        __syncthreads();
        __threadfence();   // acquire side
    }
}

// ---------------- utility ----------------
__global__ void k_zero(float* p, int n){
    int i = blockIdx.x*256 + threadIdx.x;
    if (i < n) p[i] = 0.f;
}

// f32 [rows][ldin] (first 512 cols) -> bf16 [rows][512]
__global__ void k_cvt(const float* __restrict__ in, short* __restrict__ out, int ldin){
    long idx = (long)blockIdx.x*256 + threadIdx.x;
    long r = idx >> 9; int c = idx & 511;
    out[idx] = f2bf(in[r*ldin + c]);
}

// token gather -> bf16 rows. mode 0: src flat-reshape; mode 1: tgt transpose
__global__ void k_gather_bf(const float* __restrict__ emb, const int* __restrict__ tok,
                            short* __restrict__ out, int mode){
    long idx = (long)blockIdx.x*256 + threadIdx.x;   // 2048*512
    int m = idx >> 9, e = idx & 511;
    int ti = mode ? ((m & 31)*64 + (m >> 5)) : m;
    out[idx] = f2bf(emb[(long)tok[ti]*512 + e]);
}

// ---------------- MFMA bf16 GEMM: C[m,n] = sum_k A[m,k]*B[n,k], K=512 ----------------
// STORE=1: store f32 C (ldc=N). STORE=0: atomicAdd(sumexp[m], sum_n exp(C[m,n])).
template<int STORE>
__global__ __launch_bounds__(256)
void k_mfma_gemm(const short* __restrict__ A, const short* __restrict__ B,
                 float* __restrict__ C, int ldc){
    __shared__ short As[128][72];
    __shared__ short Bs[128][72];
    int tid = threadIdx.x, l = tid & 63, w = tid >> 6;
    int wm = w >> 1, wn = w & 1;
    long m0 = (long)blockIdx.x * 128, n0 = (long)blockIdx.y * 128;
    float4v acc[4][4];
    #pragma unroll
    for (int a=0;a<4;++a)
        #pragma unroll
        for (int b=0;b<4;++b)
            #pragma unroll
            for (int e=0;e<4;++e) acc[a][b][e] = 0.f;

    for (int kb = 0; kb < 8; ++kb){
        #pragma unroll
        for (int i = tid; i < 1024; i += 256){
            int r = i >> 3, c = i & 7;
            *(uint4*)&As[r][c*8] = *(const uint4*)(A + (m0+r)*512 + kb*64 + c*8);
            *(uint4*)&Bs[r][c*8] = *(const uint4*)(B + (n0+r)*512 + kb*64 + c*8);
        }
        __syncthreads();
        #pragma unroll
        for (int ks = 0; ks < 2; ++ks){
            short8 af[4], bf[4];
            #pragma unroll
            for (int tm=0;tm<4;++tm)
                af[tm] = *(const short8*)&As[wm*64 + tm*16 + (l&15)][ks*32 + (l>>4)*8];
            #pragma unroll
            for (int tn=0;tn<4;++tn)
                bf[tn] = *(const short8*)&Bs[wn*64 + tn*16 + (l&15)][ks*32 + (l>>4)*8];
            #pragma unroll
            for (int tm=0;tm<4;++tm)
                #pragma unroll
                for (int tn=0;tn<4;++tn)
                    acc[tm][tn] = __builtin_amdgcn_mfma_f32_16x16x32_bf16(
                        af[tm], bf[tn], acc[tm][tn], 0, 0, 0);
        }
        __syncthreads();
    }

    int q = l >> 4;  // quad group
    if (STORE){
        #pragma unroll
        for (int tm=0;tm<4;++tm)
            #pragma unroll
            for (int r=0;r<4;++r){
                long m = m0 + wm*64 + tm*16 + q*4 + r;
                #pragma unroll
                for (int tn=0;tn<4;++tn)
                    C[m*ldc + n0 + wn*64 + tn*16 + (l&15)] = acc[tm][tn][r];
            }
    } else {
        #pragma unroll
        for (int tm=0;tm<4;++tm)
            #pragma unroll
            for (int r=0;r<4;++r){
                float s = 0.f;
                #pragma unroll
                for (int tn=0;tn<4;++tn) s += __expf(acc[tm][tn][r]);
                s += __shfl_xor(s, 1); s += __shfl_xor(s, 2);
                s += __shfl_xor(s, 4); s += __shfl_xor(s, 8);
                if ((l & 15) == 0)
                    atomicAdd(&C[m0 + wm*64 + tm*16 + q*4 + r], s);
            }
    }
}

// ---------------- persistent encoder ----------------
// 256 blocks x 256 threads, 1 block/CU. dir = bid>>7, j-group of 4.
// Whh slice LDS-resident across all 64 steps; c-state register-resident.
// 1 grid-sync per step.
__global__ __launch_bounds__(256, 1)
void k_encoder(const float* __restrict__ WhhF, const float* __restrict__ WhhB,
               const float* __restrict__ bF, const float* __restrict__ bB,
               const int* __restrict__ lens,
               float* __restrict__ hF, float* __restrict__ cF,
               float* __restrict__ hB, float* __restrict__ cB,
               float* __restrict__ senc)
{
    __shared__ float WS[16][516];   // 16 gate-rows x 512 (pad 4)
    __shared__ float xS[32][516];   // h stage [32][512] (pad 4)
    __shared__ float gS[32][16];    // gate partial exchange

    const int bid = blockIdx.x, tid = threadIdx.x;
    const int dir = bid >> 7, jg = bid & 127;
    const int j0 = jg * 4;
    const float* Whh  = dir ? WhhB : WhhF;
    const float* bias = dir ? bB : bF;
    const float* X = g_X[dir];
    float* hPtr = dir ? hB : hF;

    // stage W once: row nn -> gate n = (nn>>2)*512 + j0 + (nn&3)
    for (int i = tid; i < 2048; i += 256){
        int nn = i >> 7, c4 = i & 127;
        int n = (nn >> 2)*512 + j0 + (nn & 3);
        *(float4*)&WS[nn][c4*4] = *(const float4*)(Whh + (long)n*512 + c4*4);
    }

    const int nn = tid & 15, b2 = tid >> 4;        // compute map: 2 outputs (b2, b2+16)
    const int cb = tid >> 2, cjj = tid & 3;        // cell map (tid<128)
    const int len_b = lens[cb & 31];
    float c_reg = 0.f, h_reg = 0.f;

    unsigned long long ep = __hip_atomic_load(&g_rel, __ATOMIC_RELAXED, __HIP_MEMORY_SCOPE_AGENT);

    for (int s = 0; s < 64; ++s){
        if (s){
            ep++; gsync(ep);
            for (int i = tid; i < 4096; i += 256){   // stage h [32][512]
                int r = i >> 7, c4 = i & 127;
                *(float4*)&xS[r][c4*4] = *(const float4*)(hPtr + r*512 + c4*4);
            }
        }
        __syncthreads();
        float p[4] = {0.f,0.f,0.f,0.f}, q[4] = {0.f,0.f,0.f,0.f};
        if (s){
            const float* wr = &WS[nn][0];
            const float* xa = &xS[b2][0];
            const float* xb = &xS[b2 + 16][0];
            #pragma unroll 2
            for (int k = 0; k < 512; k += 16){
                #pragma unroll
                for (int u = 0; u < 4; ++u){
                    float4 w = *(const float4*)(wr + k + u*4);
                    float4 a = *(const float4*)(xa + k + u*4);
                    float4 b = *(const float4*)(xb + k + u*4);
                    p[u] += w.x*a.x + w.y*a.y + w.z*a.z + w.w*a.w;
                    q[u] += w.x*b.x + w.y*b.y + w.z*b.z + w.w*b.w;
                }
            }
        }
        gS[b2][nn]    = p[0]+p[1]+p[2]+p[3];
        gS[b2+16][nn] = q[0]+q[1]+q[2]+q[3];
        __syncthreads();
        if (tid < 128){
            int sd = dir ? 63 - s : s;
            int j = j0 + cjj;
            const float* xr = X + ((long)(sd*32 + cb))*2048;
            float g0 = gS[cb][cjj]      + xr[j]      + bias[j];
            float g1 = gS[cb][4 + cjj]  + xr[512+j]  + bias[512+j];
            float g2 = gS[cb][8 + cjj]  + xr[1024+j] + bias[1024+j];
            float g3 = gS[cb][12 + cjj] + xr[1536+j] + bias[1536+j];
            float cn = sigf(g1)*c_reg + sigf(g0)*tanhf(g2);
            float hn = sigf(g3)*tanhf(cn);
            bool valid = sd < len_b;
            c_reg = valid ? cn : c_reg;
            h_reg = valid ? hn : h_reg;
            hPtr[cb*512 + j] = h_reg;
            senc[((long)(cb*64 + sd))*1024 + dir*512 + j] = valid ? hn : 0.f;
        }
    }
    if (tid < 128){
        float* cOut = dir ? cB : cF;
        cOut[cb*512 + j0 + cjj] = c_reg;
    }
}

// ---------------- persistent decoder ----------------
// 256 blocks x 256 threads, 1 block/CU. 3 grid-syncs per step.
// Phase A: gates (Whh + Wih-att slices LDS-resident), cell with register c.
//   h-part of the gate dot is hoisted BEFORE the C->A barrier (overlap).
// Phase B: scores/softmax/ctx (b = bid>>3, col-slice = bid&7).
// Phase C: attvec (bid<128, 4 Wavec rows LDS-resident), writes att/aves.
__global__ __launch_bounds__(256, 1)
void k_decoder(const float* __restrict__ dWhh, const float* __restrict__ dWih,
               const float* __restrict__ db, const float* __restrict__ Wv,
               const float* __restrict__ satt, const float* __restrict__ senc,
               const int* __restrict__ lens,
               float* __restrict__ dech, const float* __restrict__ decc,
               float* __restrict__ attG, float* __restrict__ ctxG,
               float* __restrict__ aves)
{
    __shared__ float xS[32][516];     // stage [32][512] (pad 4)
    __shared__ float WdS[8][1028];    // 8 gate-rows x [Whh(512) | Wih-att(512)]
    __shared__ float WvS[4][1540];    // 4 Wavec rows x 1536 (bid<128)
    __shared__ float gS[32][8];
    __shared__ float scoreQ[64][5];
    __shared__ float alphaS[64];
    __shared__ float ctxP[2][128];

    const int bid = blockIdx.x, tid = threadIdx.x;
    const float* Yg = g_X[2];

    {   // stage decoder gate weights once
        int j0 = bid*2;
        for (int i = tid; i < 2048; i += 256){
            int nn = i >> 8, c4 = i & 255;
            int n = (nn >> 1)*512 + j0 + (nn & 1);
            float4 v;
            if (c4 < 128) v = *(const float4*)(dWhh + (long)n*512  + c4*4);
            else          v = *(const float4*)(dWih + (long)n*1024 + 512 + (c4-128)*4);
            *(float4*)&WdS[nn][c4*4] = v;
        }
        if (bid < 128){
            for (int i = tid; i < 1536; i += 256){
                int r = i / 384, c4 = i % 384;
                *(float4*)&WvS[r][c4*4] = *(const float4*)(Wv + (long)(bid*4+r)*1536 + c4*4);
            }
        }
    }

    // cell state in registers (tid<64): b = tid>>1, j = bid*2 + (tid&1)
    float c_reg = 0.f;
    if (tid < 64) c_reg = decc[(tid>>1)*512 + bid*2 + (tid&1)];

    const int nnA = tid & 7, bA = tid >> 3;   // phase A map: 1 output/thread
    unsigned long long ep = __hip_atomic_load(&g_rel, __ATOMIC_RELAXED, __HIP_MEMORY_SCOPE_AGENT);

    for (int t = 0; t < 64; ++t){
        // ---------- pre-barrier: stage h(t-1) + h-part gate dot ----------
        // dech(t-1) was acquired at the A(t-1)->B sync; no one writes it until
        // our cell below, which is after the C->A sync. Overlaps phase-C wait.
        for (int i = tid; i < 4096; i += 256){
            int r = i >> 7, c4 = i & 127;
            *(float4*)&xS[r][c4*4] = *(const float4*)(dech + r*512 + c4*4);
        }
        __syncthreads();
        float p[4] = {0.f,0.f,0.f,0.f};
        {
            const float* wr = &WdS[nnA][0];
            const float* xr = &xS[bA][0];
            #pragma unroll 2
            for (int k = 0; k < 512; k += 16){
                #pragma unroll
                for (int u = 0; u < 4; ++u){
                    float4 w = *(const float4*)(wr + k + u*4);
                    float4 a = *(const float4*)(xr + k + u*4);
                    p[u] += w.x*a.x + w.y*a.y + w.z*a.z + w.w*a.w;
                }
            }
        }

        if (t){ ep++; gsync(ep); }   // C(t-1) done: attG(t-1) ready

        // ---------- phase A rest: att-part + cell ----------
        if (t){
            for (int i = tid; i < 4096; i += 256){
                int r = i >> 7, c4 = i & 127;
                *(float4*)&xS[r][c4*4] = *(const float4*)(attG + r*512 + c4*4);
            }
            __syncthreads();
            const float* wr = &WdS[nnA][512];
            const float* xr = &xS[bA][0];
            #pragma unroll 2
            for (int k = 0; k < 512; k += 16){
                #pragma unroll
                for (int u = 0; u < 4; ++u){
                    float4 w = *(const float4*)(wr + k + u*4);
                    float4 a = *(const float4*)(xr + k + u*4);
                    p[u] += w.x*a.x + w.y*a.y + w.z*a.z + w.w*a.w;
                }
            }
        }
        gS[bA][nnA] = p[0]+p[1]+p[2]+p[3];
        __syncthreads();
        if (tid < 64){
            int b = tid >> 1, jj = tid & 1, j = bid*2 + jj;
            const float* yr = Yg + ((long)t*32 + b)*2048;
            float g0 = gS[b][0 + jj] + yr[j]      + db[j];
            float g1 = gS[b][2 + jj] + yr[512+j]  + db[512+j];
            float g2 = gS[b][4 + jj] + yr[1024+j] + db[1024+j];
            float g3 = gS[b][6 + jj] + yr[1536+j] + db[1536+j];
            float cn = sigf(g1)*c_reg + sigf(g0)*tanhf(g2);
            float hn = sigf(g3)*tanhf(cn);
            c_reg = cn;
            dech[b*512 + j] = hn;
        }
        ep++; gsync(ep);   // h(t) ready

        // ---------- phase B: scores -> softmax -> ctx slice ----------
        {
            int bb = bid >> 3, cs = bid & 7;
            float* hBS = &xS[0][0];   // flat 512 floats
            for (int i = tid; i < 128; i += 256)
                *(float4*)&hBS[i*4] = *(const float4*)(dech + bb*512 + i*4);
            __syncthreads();
            {
                int ss = tid >> 2, qq = tid & 3;
                const float* sar = satt + ((long)(bb*64 + ss))*512 + qq*128;
                const float* hr = hBS + qq*128;
                float u[4] = {0.f,0.f,0.f,0.f};
                #pragma unroll 2
                for (int k = 0; k < 128; k += 16){
                    #pragma unroll
                    for (int u4 = 0; u4 < 4; ++u4){
                        float4 a = *(const float4*)(sar + k + u4*4);
                        float4 h = *(const float4*)(hr  + k + u4*4);
                        u[u4] += a.x*h.x + a.y*h.y + a.z*h.z + a.w*h.w;
                    }
                }
                scoreQ[ss][qq] = u[0]+u[1]+u[2]+u[3];
            }
            __syncthreads();
            if (tid < 64){
                float sc = scoreQ[tid][0]+scoreQ[tid][1]+scoreQ[tid][2]+scoreQ[tid][3];
                if (tid >= lens[bb]) sc = -INFINITY;
                float mx = sc;
                #pragma unroll
                for (int o=32;o>0;o>>=1) mx = fmaxf(mx, __shfl_xor(mx, o));
                float e = (sc == -INFINITY) ? 0.f : __expf(sc - mx);
                float sm = e;
                #pragma unroll
                for (int o=32;o>0;o>>=1) sm += __shfl_xor(sm, o);
                alphaS[tid] = e / fmaxf(sm, 1e-30f);
            }
            __syncthreads();
            {
                int cc = tid & 127, sh = tid >> 7;
                const float* sb = senc + ((long)bb*64 + sh*32)*1024 + cs*128 + cc;
                float a0 = 0.f, a1 = 0.f;
                for (int s2 = 0; s2 < 32; s2 += 2){
                    a0 += alphaS[sh*32 + s2]     * sb[(long)s2*1024];
                    a1 += alphaS[sh*32 + s2 + 1] * sb[(long)(s2+1)*1024];
                }
                ctxP[sh][cc] = a0 + a1;
            }
            __syncthreads();
            if (tid < 128) ctxG[(bid>>3)*1024 + (bid&7)*128 + tid] = ctxP[0][tid] + ctxP[1][tid];
        }
        ep++; gsync(ep);   // ctx ready

        // ---------- phase C: attvec -> att, aves ----------
        if (bid < 128){
            int b3 = tid >> 3, nv = (tid >> 1) & 3, kq = tid & 1;
            float q[4] = {0.f,0.f,0.f,0.f};
            for (int ch = 0; ch < 3; ++ch){
                for (int i = tid; i < 4096; i += 256){
                    int r = i >> 7, c4 = i & 127;
                    float4 v;
                    if (ch == 0) v = *(const float4*)(dech + r*512 + c4*4);
                    else         v = *(const float4*)(ctxG + (long)r*1024 + (ch-1)*512 + c4*4);
                    *(float4*)&xS[r][c4*4] = v;
                }
                __syncthreads();
                const float* xr = &xS[b3][kq*256];
                const float* wr = &WvS[nv][ch*512 + kq*256];
                #pragma unroll 2
                for (int k = 0; k < 256; k += 16){
                    #pragma unroll
                    for (int u = 0; u < 4; ++u){
                        float4 w = *(const float4*)(wr + k + u*4);
                        float4 a = *(const float4*)(xr + k + u*4);
                        q[u] += w.x*a.x + w.y*a.y + w.z*a.z + w.w*a.w;
                    }
                }
                __syncthreads();
            }
            float acc = q[0]+q[1]+q[2]+q[3];
            acc += __shfl_xor(acc, 1);
            if (kq == 0){
                float v = tanhf(acc);
                int n = bid*4 + nv;
                attG[b3*512 + n] = v;
                long m = (long)t*32 + b3;
                aves[m*512 + n] = v;
                g_aves_bf[m*512 + n] = f2bf(v);
            }
        }
    }
}

__global__ void k_ccat(const float* __restrict__ cF, const float* __restrict__ cB,
                       float* __restrict__ ccat){
    int idx = blockIdx.x*256 + threadIdx.x;   // 32*1024
    int b = idx >> 10, d = idx & 1023;
    ccat[idx] = (d < 512) ? cF[b*512+d] : cB[b*512+d-512];
}

// ---------------- generic f32 tiled GEMM (satt, init) ----------------
__global__ __launch_bounds__(256)
void k_gemm(const float* __restrict__ A, const float* __restrict__ W,
            const float* __restrict__ bias, float* __restrict__ C,
            int M, int K, int lda, int ldw, int ldc){
    __shared__ float As[16][65];
    __shared__ float Wt[16][65];
    int tid = threadIdx.x;
    int m0 = blockIdx.x * 64, n0 = blockIdx.y * 64;
    int ty = tid >> 4, tx = tid & 15;
    int lm = tid >> 2, lk = (tid & 3) * 4;
    float acc[4][4] = {};
    for (int kt = 0; kt < K; kt += 16){
        float4 av;
        if (m0 + lm < M) av = *(const float4*)(A + (long)(m0+lm)*lda + kt + lk);
        else av = make_float4(0.f,0.f,0.f,0.f);
        As[lk+0][lm]=av.x; As[lk+1][lm]=av.y; As[lk+2][lm]=av.z; As[lk+3][lm]=av.w;
        float4 wv = *(const float4*)(W + (long)(n0+lm)*ldw + kt + lk);
        Wt[lk+0][lm]=wv.x; Wt[lk+1][lm]=wv.y; Wt[lk+2][lm]=wv.z; Wt[lk+3][lm]=wv.w;
        __syncthreads();
        #pragma unroll
        for (int k = 0; k < 16; ++k){
            float a0=As[k][ty*4+0], a1=As[k][ty*4+1], a2=As[k][ty*4+2], a3=As[k][ty*4+3];
            float b0=Wt[k][tx*4+0], b1=Wt[k][tx*4+1], b2=Wt[k][tx*4+2], b3=Wt[k][tx*4+3];
            acc[0][0]+=a0*b0; acc[0][1]+=a0*b1; acc[0][2]+=a0*b2; acc[0][3]+=a0*b3;
            acc[1][0]+=a1*b0; acc[1][1]+=a1*b1; acc[1][2]+=a1*b2; acc[1][3]+=a1*b3;
            acc[2][0]+=a2*b0; acc[2][1]+=a2*b1; acc[2][2]+=a2*b2; acc[2][3]+=a2*b3;
            acc[3][0]+=a3*b0; acc[3][1]+=a3*b1; acc[3][2]+=a3*b2; acc[3][3]+=a3*b3;
        }
        __syncthreads();
    }
    #pragma unroll
    for (int i=0;i<4;++i){
        int m = m0 + ty*4 + i;
        if (m >= M) continue;
        #pragma unroll
        for (int j=0;j<4;++j){
            int n = n0 + tx*4 + j;
            float v = acc[i][j];
            if (bias) v += bias[n];
            C[(long)m*ldc + n] = v;
        }
    }
}

__global__ void k_dec_init(const float* __restrict__ decc0, float* dech){
    int idx = blockIdx.x*256 + threadIdx.x;   // 16384
    dech[idx] = tanhf(decc0[idx]);
}

// ---------------- gold + final ----------------
__global__ void k_gold(const float* __restrict__ aves, const float* __restrict__ Wr,
                       const int* __restrict__ tgt, float* __restrict__ gold){
    int wid = threadIdx.x >> 6, lane = threadIdx.x & 63;
    int m = blockIdx.x*4 + wid;   // m = t*32 + b
    int t = m >> 5, b = m & 31;
    int g = tgt[b*64 + t];
    const float* arow = aves + (long)m*512;
    const float* wrow = Wr + (long)g*512;
    float p = 0.f;
    for (int k=lane; k<512; k+=64) p += arow[k]*wrow[k];
    #pragma unroll
    for (int o=32;o>0;o>>=1) p += __shfl_xor(p, o);
    if (lane == 0) gold[m] = p;
}

__global__ void k_final(const float* __restrict__ gold, const float* __restrict__ sumexp,
                        const int* __restrict__ tgt, float* __restrict__ out){
    int t = threadIdx.x;
    float a = 0.f;
    for (int b=0;b<32;++b){
        int m = t*32 + b;
        float lp = gold[m] - logf(fmaxf(sumexp[m], 1e-30f));
        if (tgt[b*64 + t] != 0) a += lp;
    }
    out[t] = a;
}

// ---------------- launch ----------------
extern "C" void kernel_launch(void* const* d_in, const int* in_sizes, int n_in,
                              void* d_out, int out_size, void* d_ws, size_t ws_size,
                              hipStream_t stream){
    const int* src_tok   = (const int*)d_in[0];
    const int* tgt_tok   = (const int*)d_in[1];
    const int* lens      = (const int*)d_in[2];
    const float* src_emb = (const float*)d_in[3];
    const float* tgt_emb = (const float*)d_in[4];
    const float* eWihF   = (const float*)d_in[5];
    const float* eWhhF   = (const float*)d_in[6];
    const float* ebF     = (const float*)d_in[7];
    const float* eWihB   = (const float*)d_in[8];
    const float* eWhhB   = (const float*)d_in[9];
    const float* ebB     = (const float*)d_in[10];
    const float* dWih    = (const float*)d_in[11];
    const float* dWhh    = (const float*)d_in[12];
    const float* db      = (const float*)d_in[13];
    const float* Wasrc   = (const float*)d_in[14];
    const float* Wavec   = (const float*)d_in[15];
    const float* Wread   = (const float*)d_in[16];
    const float* Winit   = (const float*)d_in[17];
    const float* binit   = (const float*)d_in[18];
    float* ws  = (float*)d_ws;
    float* out = (float*)d_out;

    float* senc = ws + o_senc;  float* satt = ws + o_satt; float* aves = ws + o_aves;
    float* hF = ws + o_hF; float* cF = ws + o_cF; float* hB = ws + o_hB; float* cB = ws + o_cB;
    float* sumexp = ws + o_sumexp; float* gold = ws + o_gold;
    float* ccat = ws + o_ccat;
    float* dech = ws + o_dech; float* decc = ws + o_decc;
    float* attG = ws + o_att; float* ctxG = ws + o_ctx;

    // device-symbol pointers
    float* Xf; short *WreadBf, *srcxBf, *tgtyBf, *WihFbf, *WihBbf, *dWihYbf;
    hipGetSymbolAddress((void**)&Xf, HIP_SYMBOL(g_X));
    hipGetSymbolAddress((void**)&WreadBf, HIP_SYMBOL(g_Wread_bf));
    hipGetSymbolAddress((void**)&srcxBf, HIP_SYMBOL(g_bfA));
    hipGetSymbolAddress((void**)&WihFbf, HIP_SYMBOL(g_bfW));
    tgtyBf = srcxBf + 2048L*512;
    WihBbf = WihFbf + 2048L*512;
    dWihYbf = WihFbf + 2L*2048*512;

    // zero states + sumexp
    k_zero<<<264, 256, 0, stream>>>(hF, 67584);

    // bf16 conversions + gathers
    k_cvt<<<4096, 256, 0, stream>>>(eWihF, WihFbf, 512);
    k_cvt<<<4096, 256, 0, stream>>>(eWihB, WihBbf, 512);
    k_cvt<<<4096, 256, 0, stream>>>(dWih, dWihYbf, 1024);   // cols 0..511
    k_cvt<<<64000, 256, 0, stream>>>(Wread, WreadBf, 512);
    k_gather_bf<<<4096, 256, 0, stream>>>(src_emb, src_tok, srcxBf, 0);
    k_gather_bf<<<4096, 256, 0, stream>>>(tgt_emb, tgt_tok, tgtyBf, 1);

    // x-part precompute: Xf, Xb, Yg = emb x Wih^T (MFMA)
    k_mfma_gemm<1><<<dim3(16,16), 256, 0, stream>>>(srcxBf, WihFbf, Xf, 2048);
    k_mfma_gemm<1><<<dim3(16,16), 256, 0, stream>>>(srcxBf, WihBbf, Xf + 2048L*2048, 2048);
    k_mfma_gemm<1><<<dim3(16,16), 256, 0, stream>>>(tgtyBf, dWihYbf, Xf + 2L*2048*2048, 2048);

    // encoder recurrence: ONE persistent kernel (64 steps, 63 grid-syncs)
    k_encoder<<<256, 256, 0, stream>>>(eWhhF, eWhhB, ebF, ebB, lens, hF, cF, hB, cB, senc);

    // [c_f|c_b]; src_att; decoder init
    k_ccat<<<128, 256, 0, stream>>>(cF, cB, ccat);
    k_gemm<<<dim3(32,8), 256, 0, stream>>>(senc, Wasrc, nullptr, satt, 2048, 1024, 1024, 1024, 512);
    k_gemm<<<dim3(1,8), 256, 0, stream>>>(ccat, Winit, binit, decc, 32, 1024, 1024, 1024, 512);
    k_dec_init<<<64, 256, 0, stream>>>(decc, dech);

    // decoder recurrence: ONE persistent kernel (64 steps, 191 grid-syncs)
    k_decoder<<<256, 256, 0, stream>>>(dWhh, dWih, db, Wavec, satt, senc, lens,
                                       dech, decc, attG, ctxG, aves);

    // readout: MFMA bf16 GEMM with fused exp-sum; gold; final
    short* avesBf; hipGetSymbolAddress((void**)&avesBf, HIP_SYMBOL(g_aves_bf));
    k_mfma_gemm<0><<<dim3(16,250), 256, 0, stream>>>(avesBf, WreadBf, sumexp, 0);
    k_gold<<<512, 256, 0, stream>>>(aves, Wread, tgt_tok, gold);
    k_final<<<1, 64, 0, stream>>>(gold, sumexp, tgt_tok, out);
}

// Round 3
// 5184.505 us; speedup vs baseline: 3.6884x; 1.7348x over previous
//
#include <hip/hip_runtime.h>
#include <hip/hip_bf16.h>
#include <cmath>

// All float tensors f32 (reference: jnp.float32). Output f32 [64].
// B=32, S=64, T=64, E=512, H=512, 4H=2048, V=32000

__device__ __forceinline__ float sigf(float x){ return 1.0f/(1.0f+__expf(-x)); }
__device__ __forceinline__ short f2bf(float x){
    unsigned u = __builtin_bit_cast(unsigned, x);
    u += 0x7fff + ((u >> 16) & 1);
    return (short)(u >> 16);
}

typedef __attribute__((ext_vector_type(8))) short short8;   // 8 bf16 (4 VGPR)
typedef __attribute__((ext_vector_type(4))) float float4v;  // 4 f32 acc

// ---------------- workspace (d_ws) layout, proven <=22.5MB ----------------
constexpr long o_senc   = 0;                     // [B][S][1024]
constexpr long o_satt   = o_senc + 32L*64*1024;  // [B][S][512]
constexpr long o_aves   = o_satt + 32L*64*512;   // [T*B][512] f32
constexpr long o_hF     = o_aves + 64L*32*512;   // zero-block start
constexpr long o_cF     = o_hF + 32L*512;
constexpr long o_hB     = o_cF + 32L*512;
constexpr long o_cB     = o_hB + 32L*512;
constexpr long o_sumexp = o_cB + 32L*512;        // 2048 (zero block = 67584 floats)
constexpr long o_gold   = o_sumexp + 2048;
constexpr long o_ccat   = o_gold + 2048;         // [32][1024]
constexpr long o_dech   = o_ccat + 32L*1024;
constexpr long o_decc   = o_dech + 32L*512;
constexpr long o_att    = o_decc + 32L*512;      // attG [32][512]
constexpr long o_ctx    = o_att + 32L*512;       // [32][1024]

// ---------------- static device buffers (independent of ws_size) ----------------
__device__ __align__(16) float g_X[3][2048L*2048];     // Xf, Xb, Yg (raw x-part gates)
__device__ __align__(16) short g_Wread_bf[32000L*512];
__device__ __align__(16) short g_bfA[2][2048L*512];    // srcx_bf, tgty_bf
__device__ __align__(16) short g_bfW[3][2048L*512];    // WihF_bf, WihB_bf, dWihY_bf
__device__ __align__(16) short g_aves_bf[2048L*512];

// ---------------- device-scope (L2-bypassing) access helpers ----------------
// Mutable cross-block state is accessed ONLY through these (sc1-flagged ops,
// coherent at the Infinity-Cache point) -> no wbl2/inv fences needed anywhere.
__device__ __forceinline__ float ld_devf(const float* p){
    return __hip_atomic_load(p, __ATOMIC_RELAXED, __HIP_MEMORY_SCOPE_AGENT);
}
__device__ __forceinline__ void st_devf(float* p, float v){
    __hip_atomic_store(p, v, __ATOMIC_RELAXED, __HIP_MEMORY_SCOPE_AGENT);
}
__device__ __forceinline__ float2 ld_devf2(const float* p){
    unsigned long long u = __hip_atomic_load((const unsigned long long*)p,
                                             __ATOMIC_RELAXED, __HIP_MEMORY_SCOPE_AGENT);
    return __builtin_bit_cast(float2, u);
}

// ---------------- grid barrier (persistent kernels) ----------------
// Two-level flag barrier, monotonic epochs, never reset (graph-replay safe).
// NO threadfence: all shared data moves via device-scope ops (see above);
// __syncthreads() drains vmcnt(0) (compiler-emitted) so stores are at the
// coherence point before the arrival flag goes out.
__device__ __align__(128) unsigned long long g_arr[256][16];  // 128B stride/block
__device__ unsigned long long g_rel = 0ull;

__device__ __forceinline__ unsigned long long ld_flag(const unsigned long long* p){
    return __hip_atomic_load(p, __ATOMIC_RELAXED, __HIP_MEMORY_SCOPE_AGENT);
}
__device__ __forceinline__ void st_flag(unsigned long long* p, unsigned long long v){
    __hip_atomic_store(p, v, __ATOMIC_RELAXED, __HIP_MEMORY_SCOPE_AGENT);
}

__device__ __forceinline__ void gsync(unsigned long long ep){
    asm volatile("s_waitcnt vmcnt(0)" ::: "memory");  // own wave's stores drained
    __syncthreads();                                   // all waves drained (barrier waitcnt)
    if (blockIdx.x == 0){
        int tid = threadIdx.x;
        if (tid > 0){   // thread t waits for block t's arrival flag
            while (ld_flag(&g_arr[tid][0]) < ep)
                __builtin_amdgcn_s_sleep(1);
        }
        __syncthreads();
        if (tid == 0) st_flag(&g_rel, ep);
    } else {
        if (threadIdx.x == 0){
            st_flag(&g_arr[blockIdx.x][0], ep);
            while (ld_flag(&g_rel) < ep)
                __builtin_amdgcn_s_sleep(1);
        }
        __syncthreads();
    }
    asm volatile("" ::: "memory");   // compiler barrier: no hoisting above the poll
}

// ---------------- utility ----------------
__global__ void k_zero(float* p, int n){
    int i = blockIdx.x*256 + threadIdx.x;
    if (i < n) p[i] = 0.f;
}

// f32 [rows][ldin] (first 512 cols) -> bf16 [rows][512]
__global__ void k_cvt(const float* __restrict__ in, short* __restrict__ out, int ldin){
    long idx = (long)blockIdx.x*256 + threadIdx.x;
    long r = idx >> 9; int c = idx & 511;
    out[idx] = f2bf(in[r*ldin + c]);
}

// token gather -> bf16 rows. mode 0: src flat-reshape; mode 1: tgt transpose
__global__ void k_gather_bf(const float* __restrict__ emb, const int* __restrict__ tok,
                            short* __restrict__ out, int mode){
    long idx = (long)blockIdx.x*256 + threadIdx.x;   // 2048*512
    int m = idx >> 9, e = idx & 511;
    int ti = mode ? ((m & 31)*64 + (m >> 5)) : m;
    out[idx] = f2bf(emb[(long)tok[ti]*512 + e]);
}

// ---------------- MFMA bf16 GEMM: C[m,n] = sum_k A[m,k]*B[n,k], K=512 ----------------
// STORE=1: store f32 C (ldc=N). STORE=0: atomicAdd(sumexp[m], sum_n exp(C[m,n])).
template<int STORE>
__global__ __launch_bounds__(256)
void k_mfma_gemm(const short* __restrict__ A, const short* __restrict__ B,
                 float* __restrict__ C, int ldc){
    __shared__ short As[128][72];
    __shared__ short Bs[128][72];
    int tid = threadIdx.x, l = tid & 63, w = tid >> 6;
    int wm = w >> 1, wn = w & 1;
    long m0 = (long)blockIdx.x * 128, n0 = (long)blockIdx.y * 128;
    float4v acc[4][4];
    #pragma unroll
    for (int a=0;a<4;++a)
        #pragma unroll
        for (int b=0;b<4;++b)
            #pragma unroll
            for (int e=0;e<4;++e) acc[a][b][e] = 0.f;

    for (int kb = 0; kb < 8; ++kb){
        #pragma unroll
        for (int i = tid; i < 1024; i += 256){
            int r = i >> 3, c = i & 7;
            *(uint4*)&As[r][c*8] = *(const uint4*)(A + (m0+r)*512 + kb*64 + c*8);
            *(uint4*)&Bs[r][c*8] = *(const uint4*)(B + (n0+r)*512 + kb*64 + c*8);
        }
        __syncthreads();
        #pragma unroll
        for (int ks = 0; ks < 2; ++ks){
            short8 af[4], bf[4];
            #pragma unroll
            for (int tm=0;tm<4;++tm)
                af[tm] = *(const short8*)&As[wm*64 + tm*16 + (l&15)][ks*32 + (l>>4)*8];
            #pragma unroll
            for (int tn=0;tn<4;++tn)
                bf[tn] = *(const short8*)&Bs[wn*64 + tn*16 + (l&15)][ks*32 + (l>>4)*8];
            #pragma unroll
            for (int tm=0;tm<4;++tm)
                #pragma unroll
                for (int tn=0;tn<4;++tn)
                    acc[tm][tn] = __builtin_amdgcn_mfma_f32_16x16x32_bf16(
                        af[tm], bf[tn], acc[tm][tn], 0, 0, 0);
        }
        __syncthreads();
    }

    int q = l >> 4;  // quad group
    if (STORE){
        #pragma unroll
        for (int tm=0;tm<4;++tm)
            #pragma unroll
            for (int r=0;r<4;++r){
                long m = m0 + wm*64 + tm*16 + q*4 + r;
                #pragma unroll
                for (int tn=0;tn<4;++tn)
                    C[m*ldc + n0 + wn*64 + tn*16 + (l&15)] = acc[tm][tn][r];
            }
    } else {
        #pragma unroll
        for (int tm=0;tm<4;++tm)
            #pragma unroll
            for (int r=0;r<4;++r){
                float s = 0.f;
                #pragma unroll
                for (int tn=0;tn<4;++tn) s += __expf(acc[tm][tn][r]);
                s += __shfl_xor(s, 1); s += __shfl_xor(s, 2);
                s += __shfl_xor(s, 4); s += __shfl_xor(s, 8);
                if ((l & 15) == 0)
                    atomicAdd(&C[m0 + wm*64 + tm*16 + q*4 + r], s);
            }
    }
}

// ---------------- persistent encoder ----------------
// 256 blocks x 256 threads, 1 block/CU. dir = bid>>7, j-group of 4.
// Whh slice LDS-resident across all 64 steps; c-state register-resident.
// h exchange via device-scope (sc1) ops; 1 grid-sync per step, no fences.
__global__ __launch_bounds__(256, 1)
void k_encoder(const float* __restrict__ WhhF, const float* __restrict__ WhhB,
               const float* __restrict__ bF, const float* __restrict__ bB,
               const int* __restrict__ lens,
               float* __restrict__ hF, float* __restrict__ cF,
               float* __restrict__ hB, float* __restrict__ cB,
               float* __restrict__ senc)
{
    __shared__ float WS[16][516];   // 16 gate-rows x 512 (pad 4)
    __shared__ float xS[32][516];   // h stage [32][512] (pad 4)
    __shared__ float gS[32][16];    // gate partial exchange

    const int bid = blockIdx.x, tid = threadIdx.x;
    const int dir = bid >> 7, jg = bid & 127;
    const int j0 = jg * 4;
    const float* Whh  = dir ? WhhB : WhhF;
    const float* bias = dir ? bB : bF;
    const float* X = g_X[dir];
    float* hPtr = dir ? hB : hF;

    // stage W once: row nn -> gate n = (nn>>2)*512 + j0 + (nn&3)
    for (int i = tid; i < 2048; i += 256){
        int nn = i >> 7, c4 = i & 127;
        int n = (nn >> 2)*512 + j0 + (nn & 3);
        *(float4*)&WS[nn][c4*4] = *(const float4*)(Whh + (long)n*512 + c4*4);
    }

    const int nn = tid & 15, b2 = tid >> 4;        // compute map: 2 outputs (b2, b2+16)
    const int cb = tid >> 2, cjj = tid & 3;        // cell map (tid<128)
    const int len_b = lens[cb & 31];
    float c_reg = 0.f, h_reg = 0.f;

    unsigned long long ep = ld_flag(&g_rel);

    for (int s = 0; s < 64; ++s){
        if (s){
            ep++; gsync(ep);
            for (int i = tid; i < 8192; i += 256){   // stage h [32][512] (device-scope)
                float2 v = ld_devf2(hPtr + i*2);
                xS[i >> 8][(i & 255)*2]     = v.x;
                xS[i >> 8][(i & 255)*2 + 1] = v.y;
            }
        }
        __syncthreads();
        float p[4] = {0.f,0.f,0.f,0.f}, q[4] = {0.f,0.f,0.f,0.f};
        if (s){
            const float* wr = &WS[nn][0];
            const float* xa = &xS[b2][0];
            const float* xb = &xS[b2 + 16][0];
            #pragma unroll 2
            for (int k = 0; k < 512; k += 16){
                #pragma unroll
                for (int u = 0; u < 4; ++u){
                    float4 w = *(const float4*)(wr + k + u*4);
                    float4 a = *(const float4*)(xa + k + u*4);
                    float4 b = *(const float4*)(xb + k + u*4);
                    p[u] += w.x*a.x + w.y*a.y + w.z*a.z + w.w*a.w;
                    q[u] += w.x*b.x + w.y*b.y + w.z*b.z + w.w*b.w;
                }
            }
        }
        gS[b2][nn]    = p[0]+p[1]+p[2]+p[3];
        gS[b2+16][nn] = q[0]+q[1]+q[2]+q[3];
        __syncthreads();
        if (tid < 128){
            int sd = dir ? 63 - s : s;
            int j = j0 + cjj;
            const float* xr = X + ((long)(sd*32 + cb))*2048;
            float g0 = gS[cb][cjj]      + xr[j]      + bias[j];
            float g1 = gS[cb][4 + cjj]  + xr[512+j]  + bias[512+j];
            float g2 = gS[cb][8 + cjj]  + xr[1024+j] + bias[1024+j];
            float g3 = gS[cb][12 + cjj] + xr[1536+j] + bias[1536+j];
            float cn = sigf(g1)*c_reg + sigf(g0)*tanhf(g2);
            float hn = sigf(g3)*tanhf(cn);
            bool valid = sd < len_b;
            c_reg = valid ? cn : c_reg;
            h_reg = valid ? hn : h_reg;
            st_devf(hPtr + cb*512 + j, h_reg);
            senc[((long)(cb*64 + sd))*1024 + dir*512 + j] = valid ? hn : 0.f;
        }
    }
    if (tid < 128){
        float* cOut = dir ? cB : cF;
        cOut[cb*512 + j0 + cjj] = c_reg;
    }
}

// ---------------- persistent decoder ----------------
// 256 blocks x 256 threads, 1 block/CU. 3 grid-syncs per step, no fences.
// Mutable cross-block state (dech, attG, ctxG) via device-scope ops only;
// read-only satt/senc/Yg stay plain (L2-resident across all steps).
// Phase A: gates (Whh + Wih-att slices LDS-resident), cell with register c.
//   h-part of the gate dot is hoisted BEFORE the C->A barrier (overlap).
// Phase B: scores/softmax/ctx (b = bid>>3, col-slice = bid&7).
// Phase C: attvec (bid<128, channel order {ctx0,ctx1,dech} so xS ends
//   holding dech(t) and the next pre-barrier stage is skipped).
__global__ __launch_bounds__(256, 1)
void k_decoder(const float* __restrict__ dWhh, const float* __restrict__ dWih,
               const float* __restrict__ db, const float* __restrict__ Wv,
               const float* __restrict__ satt, const float* __restrict__ senc,
               const int* __restrict__ lens,
               float* __restrict__ dech, const float* __restrict__ decc,
               float* __restrict__ attG, float* __restrict__ ctxG,
               float* __restrict__ aves)
{
    __shared__ float xS[32][516];     // stage [32][512] (pad 4)
    __shared__ float WdS[8][1028];    // 8 gate-rows x [Whh(512) | Wih-att(512)]
    __shared__ float WvS[4][1540];    // 4 Wavec rows x 1536 (bid<128)
    __shared__ float gS[32][8];
    __shared__ float scoreQ[64][5];
    __shared__ float alphaS[64];
    __shared__ float ctxP[2][128];

    const int bid = blockIdx.x, tid = threadIdx.x;
    const float* Yg = g_X[2];

    {   // stage decoder gate weights once
        int j0 = bid*2;
        for (int i = tid; i < 2048; i += 256){
            int nn = i >> 8, c4 = i & 255;
            int n = (nn >> 1)*512 + j0 + (nn & 1);
            float4 v;
            if (c4 < 128) v = *(const float4*)(dWhh + (long)n*512  + c4*4);
            else          v = *(const float4*)(dWih + (long)n*1024 + 512 + (c4-128)*4);
            *(float4*)&WdS[nn][c4*4] = v;
        }
        if (bid < 128){
            for (int i = tid; i < 1536; i += 256){
                int r = i / 384, c4 = i % 384;
                *(float4*)&WvS[r][c4*4] = *(const float4*)(Wv + (long)(bid*4+r)*1536 + c4*4);
            }
        }
    }

    // cell state in registers (tid<64): b = tid>>1, j = bid*2 + (tid&1)
    float c_reg = 0.f;
    if (tid < 64) c_reg = decc[(tid>>1)*512 + bid*2 + (tid&1)];

    const int nnA = tid & 7, bA = tid >> 3;   // phase A map: 1 output/thread
    unsigned long long ep = ld_flag(&g_rel);

    for (int t = 0; t < 64; ++t){
        // ---------- pre-barrier: stage h(t-1) + h-part gate dot ----------
        // dech(t-1) stable between A(t-1) and A(t); overlaps other blocks' C.
        // bid<128 && t>0: xS already holds dech(t-1) from phase C's last channel.
        if (t == 0 || bid >= 128){
            for (int i = tid; i < 8192; i += 256){
                float2 v = ld_devf2(dech + i*2);
                xS[i >> 8][(i & 255)*2]     = v.x;
                xS[i >> 8][(i & 255)*2 + 1] = v.y;
            }
        }
        __syncthreads();
        float p[4] = {0.f,0.f,0.f,0.f};
        {
            const float* wr = &WdS[nnA][0];
            const float* xr = &xS[bA][0];
            #pragma unroll 2
            for (int k = 0; k < 512; k += 16){
                #pragma unroll
                for (int u = 0; u < 4; ++u){
                    float4 w = *(const float4*)(wr + k + u*4);
                    float4 a = *(const float4*)(xr + k + u*4);
                    p[u] += w.x*a.x + w.y*a.y + w.z*a.z + w.w*a.w;
                }
            }
        }

        if (t){ ep++; gsync(ep); }   // C(t-1) done: attG(t-1) ready

        // ---------- phase A rest: att-part + cell ----------
        if (t){
            for (int i = tid; i < 8192; i += 256){
                float2 v = ld_devf2(attG + i*2);
                xS[i >> 8][(i & 255)*2]     = v.x;
                xS[i >> 8][(i & 255)*2 + 1] = v.y;
            }
            __syncthreads();
            const float* wr = &WdS[nnA][512];
            const float* xr = &xS[bA][0];
            #pragma unroll 2
            for (int k = 0; k < 512; k += 16){
                #pragma unroll
                for (int u = 0; u < 4; ++u){
                    float4 w = *(const float4*)(wr + k + u*4);
                    float4 a = *(const float4*)(xr + k + u*4);
                    p[u] += w.x*a.x + w.y*a.y + w.z*a.z + w.w*a.w;
                }
            }
        }
        gS[bA][nnA] = p[0]+p[1]+p[2]+p[3];
        __syncthreads();
        if (tid < 64){
            int b = tid >> 1, jj = tid & 1, j = bid*2 + jj;
            const float* yr = Yg + ((long)t*32 + b)*2048;
            float g0 = gS[b][0 + jj] + yr[j]      + db[j];
            float g1 = gS[b][2 + jj] + yr[512+j]  + db[512+j];
            float g2 = gS[b][4 + jj] + yr[1024+j] + db[1024+j];
            float g3 = gS[b][6 + jj] + yr[1536+j] + db[1536+j];
            float cn = sigf(g1)*c_reg + sigf(g0)*tanhf(g2);
            float hn = sigf(g3)*tanhf(cn);
            c_reg = cn;
            st_devf(dech + b*512 + j, hn);
        }
        ep++; gsync(ep);   // h(t) ready

        // ---------- phase B: scores -> softmax -> ctx slice ----------
        {
            int bb = bid >> 3, cs = bid & 7;
            float* hBS = &xS[0][0];   // flat 512 floats
            {
                float2 v = ld_devf2(dech + bb*512 + tid*2);
                hBS[tid*2] = v.x; hBS[tid*2 + 1] = v.y;
            }
            __syncthreads();
            {
                int ss = tid >> 2, qq = tid & 3;
                const float* sar = satt + ((long)(bb*64 + ss))*512 + qq*128;
                const float* hr = hBS + qq*128;
                float u[4] = {0.f,0.f,0.f,0.f};
                #pragma unroll 2
                for (int k = 0; k < 128; k += 16){
                    #pragma unroll
                    for (int u4 = 0; u4 < 4; ++u4){
                        float4 a = *(const float4*)(sar + k + u4*4);
                        float4 h = *(const float4*)(hr  + k + u4*4);
                        u[u4] += a.x*h.x + a.y*h.y + a.z*h.z + a.w*h.w;
                    }
                }
                scoreQ[ss][qq] = u[0]+u[1]+u[2]+u[3];
            }
            __syncthreads();
            if (tid < 64){
                float sc = scoreQ[tid][0]+scoreQ[tid][1]+scoreQ[tid][2]+scoreQ[tid][3];
                if (tid >= lens[bb]) sc = -INFINITY;
                float mx = sc;
                #pragma unroll
                for (int o=32;o>0;o>>=1) mx = fmaxf(mx, __shfl_xor(mx, o));
                float e = (sc == -INFINITY) ? 0.f : __expf(sc - mx);
                float sm = e;
                #pragma unroll
                for (int o=32;o>0;o>>=1) sm += __shfl_xor(sm, o);
                alphaS[tid] = e / fmaxf(sm, 1e-30f);
            }
            __syncthreads();
            {
                int cc = tid & 127, sh = tid >> 7;
                const float* sb = senc + ((long)bb*64 + sh*32)*1024 + cs*128 + cc;
                float a0 = 0.f, a1 = 0.f;
                for (int s2 = 0; s2 < 32; s2 += 2){
                    a0 += alphaS[sh*32 + s2]     * sb[(long)s2*1024];
                    a1 += alphaS[sh*32 + s2 + 1] * sb[(long)(s2+1)*1024];
                }
                ctxP[sh][cc] = a0 + a1;
            }
            __syncthreads();
            if (tid < 128)
                st_devf(ctxG + (bid>>3)*1024 + (bid&7)*128 + tid,
                        ctxP[0][tid] + ctxP[1][tid]);
        }
        ep++; gsync(ep);   // ctx ready

        // ---------- phase C: attvec -> att, aves ----------
        if (bid < 128){
            int b3 = tid >> 3, nv = (tid >> 1) & 3, kq = tid & 1;
            float q[4] = {0.f,0.f,0.f,0.f};
            const int chord[3] = {1, 2, 0};   // dech staged LAST (reused next step)
            #pragma unroll
            for (int ci = 0; ci < 3; ++ci){
                int ch = chord[ci];
                __syncthreads();
                for (int i = tid; i < 8192; i += 256){
                    float2 v;
                    if (ch == 0) v = ld_devf2(dech + i*2);
                    else         v = ld_devf2(ctxG + (long)(i>>8)*1024 + (ch-1)*512 + (i&255)*2);
                    xS[i >> 8][(i & 255)*2]     = v.x;
                    xS[i >> 8][(i & 255)*2 + 1] = v.y;
                }
                __syncthreads();
                const float* xr = &xS[b3][kq*256];
                const float* wr = &WvS[nv][ch*512 + kq*256];
                #pragma unroll 2
                for (int k = 0; k < 256; k += 16){
                    #pragma unroll
                    for (int u = 0; u < 4; ++u){
                        float4 w = *(const float4*)(wr + k + u*4);
                        float4 a = *(const float4*)(xr + k + u*4);
                        q[u] += w.x*a.x + w.y*a.y + w.z*a.z + w.w*a.w;
                    }
                }
            }
            float acc = q[0]+q[1]+q[2]+q[3];
            acc += __shfl_xor(acc, 1);
            if (kq == 0){
                float v = tanhf(acc);
                int n = bid*4 + nv;
                st_devf(attG + b3*512 + n, v);
                long m = (long)t*32 + b3;
                aves[m*512 + n] = v;
                g_aves_bf[m*512 + n] = f2bf(v);
            }
        }
    }
}

__global__ void k_ccat(const float* __restrict__ cF, const float* __restrict__ cB,
                       float* __restrict__ ccat){
    int idx = blockIdx.x*256 + threadIdx.x;   // 32*1024
    int b = idx >> 10, d = idx & 1023;
    ccat[idx] = (d < 512) ? cF[b*512+d] : cB[b*512+d-512];
}

// ---------------- generic f32 tiled GEMM (satt, init) ----------------
__global__ __launch_bounds__(256)
void k_gemm(const float* __restrict__ A, const float* __restrict__ W,
            const float* __restrict__ bias, float* __restrict__ C,
            int M, int K, int lda, int ldw, int ldc){
    __shared__ float As[16][65];
    __shared__ float Wt[16][65];
    int tid = threadIdx.x;
    int m0 = blockIdx.x * 64, n0 = blockIdx.y * 64;
    int ty = tid >> 4, tx = tid & 15;
    int lm = tid >> 2, lk = (tid & 3) * 4;
    float acc[4][4] = {};
    for (int kt = 0; kt < K; kt += 16){
        float4 av;
        if (m0 + lm < M) av = *(const float4*)(A + (long)(m0+lm)*lda + kt + lk);
        else av = make_float4(0.f,0.f,0.f,0.f);
        As[lk+0][lm]=av.x; As[lk+1][lm]=av.y; As[lk+2][lm]=av.z; As[lk+3][lm]=av.w;
        float4 wv = *(const float4*)(W + (long)(n0+lm)*ldw + kt + lk);
        Wt[lk+0][lm]=wv.x; Wt[lk+1][lm]=wv.y; Wt[lk+2][lm]=wv.z; Wt[lk+3][lm]=wv.w;
        __syncthreads();
        #pragma unroll
        for (int k = 0; k < 16; ++k){
            float a0=As[k][ty*4+0], a1=As[k][ty*4+1], a2=As[k][ty*4+2], a3=As[k][ty*4+3];
            float b0=Wt[k][tx*4+0], b1=Wt[k][tx*4+1], b2=Wt[k][tx*4+2], b3=Wt[k][tx*4+3];
            acc[0][0]+=a0*b0; acc[0][1]+=a0*b1; acc[0][2]+=a0*b2; acc[0][3]+=a0*b3;
            acc[1][0]+=a1*b0; acc[1][1]+=a1*b1; acc[1][2]+=a1*b2; acc[1][3]+=a1*b3;
            acc[2][0]+=a2*b0; acc[2][1]+=a2*b1; acc[2][2]+=a2*b2; acc[2][3]+=a2*b3;
            acc[3][0]+=a3*b0; acc[3][1]+=a3*b1; acc[3][2]+=a3*b2; acc[3][3]+=a3*b3;
        }
        __syncthreads();
    }
    #pragma unroll
    for (int i=0;i<4;++i){
        int m = m0 + ty*4 + i;
        if (m >= M) continue;
        #pragma unroll
        for (int j=0;j<4;++j){
            int n = n0 + tx*4 + j;
            float v = acc[i][j];
            if (bias) v += bias[n];
            C[(long)m*ldc + n] = v;
        }
    }
}

__global__ void k_dec_init(const float* __restrict__ decc0, float* dech){
    int idx = blockIdx.x*256 + threadIdx.x;   // 16384
    dech[idx] = tanhf(decc0[idx]);
}

// ---------------- gold + final ----------------
__global__ void k_gold(const float* __restrict__ aves, const float* __restrict__ Wr,
                       const int* __restrict__ tgt, float* __restrict__ gold){
    int wid = threadIdx.x >> 6, lane = threadIdx.x & 63;
    int m = blockIdx.x*4 + wid;   // m = t*32 + b
    int t = m >> 5, b = m & 31;
    int g = tgt[b*64 + t];
    const float* arow = aves + (long)m*512;
    const float* wrow = Wr + (long)g*512;
    float p = 0.f;
    for (int k=lane; k<512; k+=64) p += arow[k]*wrow[k];
    #pragma unroll
    for (int o=32;o>0;o>>=1) p += __shfl_xor(p, o);
    if (lane == 0) gold[m] = p;
}

__global__ void k_final(const float* __restrict__ gold, const float* __restrict__ sumexp,
                        const int* __restrict__ tgt, float* __restrict__ out){
    int t = threadIdx.x;
    float a = 0.f;
    for (int b=0;b<32;++b){
        int m = t*32 + b;
        float lp = gold[m] - logf(fmaxf(sumexp[m], 1e-30f));
        if (tgt[b*64 + t] != 0) a += lp;
    }
    out[t] = a;
}

// ---------------- launch ----------------
extern "C" void kernel_launch(void* const* d_in, const int* in_sizes, int n_in,
                              void* d_out, int out_size, void* d_ws, size_t ws_size,
                              hipStream_t stream){
    const int* src_tok   = (const int*)d_in[0];
    const int* tgt_tok   = (const int*)d_in[1];
    const int* lens      = (const int*)d_in[2];
    const float* src_emb = (const float*)d_in[3];
    const float* tgt_emb = (const float*)d_in[4];
    const float* eWihF   = (const float*)d_in[5];
    const float* eWhhF   = (const float*)d_in[6];
    const float* ebF     = (const float*)d_in[7];
    const float* eWihB   = (const float*)d_in[8];
    const float* eWhhB   = (const float*)d_in[9];
    const float* ebB     = (const float*)d_in[10];
    const float* dWih    = (const float*)d_in[11];
    const float* dWhh    = (const float*)d_in[12];
    const float* db      = (const float*)d_in[13];
    const float* Wasrc   = (const float*)d_in[14];
    const float* Wavec   = (const float*)d_in[15];
    const float* Wread   = (const float*)d_in[16];
    const float* Winit   = (const float*)d_in[17];
    const float* binit   = (const float*)d_in[18];
    float* ws  = (float*)d_ws;
    float* out = (float*)d_out;

    float* senc = ws + o_senc;  float* satt = ws + o_satt; float* aves = ws + o_aves;
    float* hF = ws + o_hF; float* cF = ws + o_cF; float* hB = ws + o_hB; float* cB = ws + o_cB;
    float* sumexp = ws + o_sumexp; float* gold = ws + o_gold;
    float* ccat = ws + o_ccat;
    float* dech = ws + o_dech; float* decc = ws + o_decc;
    float* attG = ws + o_att; float* ctxG = ws + o_ctx;

    // device-symbol pointers
    float* Xf; short *WreadBf, *srcxBf, *tgtyBf, *WihFbf, *WihBbf, *dWihYbf;
    hipGetSymbolAddress((void**)&Xf, HIP_SYMBOL(g_X));
    hipGetSymbolAddress((void**)&WreadBf, HIP_SYMBOL(g_Wread_bf));
    hipGetSymbolAddress((void**)&srcxBf, HIP_SYMBOL(g_bfA));
    hipGetSymbolAddress((void**)&WihFbf, HIP_SYMBOL(g_bfW));
    tgtyBf = srcxBf + 2048L*512;
    WihBbf = WihFbf + 2048L*512;
    dWihYbf = WihFbf + 2L*2048*512;

    // zero states + sumexp
    k_zero<<<264, 256, 0, stream>>>(hF, 67584);

    // bf16 conversions + gathers
    k_cvt<<<4096, 256, 0, stream>>>(eWihF, WihFbf, 512);
    k_cvt<<<4096, 256, 0, stream>>>(eWihB, WihBbf, 512);
    k_cvt<<<4096, 256, 0, stream>>>(dWih, dWihYbf, 1024);   // cols 0..511
    k_cvt<<<64000, 256, 0, stream>>>(Wread, WreadBf, 512);
    k_gather_bf<<<4096, 256, 0, stream>>>(src_emb, src_tok, srcxBf, 0);
    k_gather_bf<<<4096, 256, 0, stream>>>(tgt_emb, tgt_tok, tgtyBf, 1);

    // x-part precompute: Xf, Xb, Yg = emb x Wih^T (MFMA)
    k_mfma_gemm<1><<<dim3(16,16), 256, 0, stream>>>(srcxBf, WihFbf, Xf, 2048);
    k_mfma_gemm<1><<<dim3(16,16), 256, 0, stream>>>(srcxBf, WihBbf, Xf + 2048L*2048, 2048);
    k_mfma_gemm<1><<<dim3(16,16), 256, 0, stream>>>(tgtyBf, dWihYbf, Xf + 2L*2048*2048, 2048);

    // encoder recurrence: ONE persistent kernel (64 steps, 63 grid-syncs)
    k_encoder<<<256, 256, 0, stream>>>(eWhhF, eWhhB, ebF, ebB, lens, hF, cF, hB, cB, senc);

    // [c_f|c_b]; src_att; decoder init
    k_ccat<<<128, 256, 0, stream>>>(cF, cB, ccat);
    k_gemm<<<dim3(32,8), 256, 0, stream>>>(senc, Wasrc, nullptr, satt, 2048, 1024, 1024, 1024, 512);
    k_gemm<<<dim3(1,8), 256, 0, stream>>>(ccat, Winit, binit, decc, 32, 1024, 1024, 1024, 512);
    k_dec_init<<<64, 256, 0, stream>>>(decc, dech);

    // decoder recurrence: ONE persistent kernel (64 steps, 191 grid-syncs)
    k_decoder<<<256, 256, 0, stream>>>(dWhh, dWih, db, Wavec, satt, senc, lens,
                                       dech, decc, attG, ctxG, aves);

    // readout: MFMA bf16 GEMM with fused exp-sum; gold; final
    short* avesBf; hipGetSymbolAddress((void**)&avesBf, HIP_SYMBOL(g_aves_bf));
    k_mfma_gemm<0><<<dim3(16,250), 256, 0, stream>>>(avesBf, WreadBf, sumexp, 0);
    k_gold<<<512, 256, 0, stream>>>(aves, Wread, tgt_tok, gold);
    k_final<<<1, 64, 0, stream>>>(gold, sumexp, tgt_tok, out);
}

// Round 4
// 4155.074 us; speedup vs baseline: 4.6023x; 1.2478x over previous
//
#include <hip/hip_runtime.h>
#include <hip/hip_bf16.h>
#include <cmath>

// All float tensors f32 (reference: jnp.float32). Output f32 [64].
// B=32, S=64, T=64, E=512, H=512, 4H=2048, V=32000

__device__ __forceinline__ float sigf(float x){ return 1.0f/(1.0f+__expf(-x)); }
__device__ __forceinline__ short f2bf(float x){
    unsigned u = __builtin_bit_cast(unsigned, x);
    u += 0x7fff + ((u >> 16) & 1);
    return (short)(u >> 16);
}

typedef __attribute__((ext_vector_type(8))) short short8;   // 8 bf16 (4 VGPR)
typedef __attribute__((ext_vector_type(4))) float float4v;  // 4 f32 acc

// ---------------- workspace (d_ws) layout, proven <=22.5MB ----------------
constexpr long o_senc   = 0;                     // [B][S][1024]
constexpr long o_satt   = o_senc + 32L*64*1024;  // [B][S][512]
constexpr long o_aves   = o_satt + 32L*64*512;   // [T*B][512] f32
constexpr long o_hF     = o_aves + 64L*32*512;   // zero-block start
constexpr long o_cF     = o_hF + 32L*512;
constexpr long o_hB     = o_cF + 32L*512;
constexpr long o_cB     = o_hB + 32L*512;
constexpr long o_sumexp = o_cB + 32L*512;        // 2048 (zero block = 67584 floats)
constexpr long o_gold   = o_sumexp + 2048;
constexpr long o_ccat   = o_gold + 2048;         // [32][1024]
constexpr long o_dech   = o_ccat + 32L*1024;
constexpr long o_decc   = o_dech + 32L*512;
constexpr long o_att    = o_decc + 32L*512;      // attG [32][512]
constexpr long o_sv     = o_att + 32L*512;       // sv [B*S][512] = Wv_ctx . senc
// end = o_sv + 2048*512 = 5,394,432 floats = 20.6 MiB  (<= 22.5 proven)

// ---------------- static device buffers (independent of ws_size) ----------------
__device__ __align__(16) float g_X[3][2048L*2048];     // Xf, Xb, Yg (raw x-part gates)
__device__ __align__(16) short g_Wread_bf[32000L*512];
__device__ __align__(16) short g_bfA[2][2048L*512];    // srcx_bf, tgty_bf
__device__ __align__(16) short g_bfW[3][2048L*512];    // WihF_bf, WihB_bf, dWihY_bf
__device__ __align__(16) short g_aves_bf[2048L*512];

// ---------------- device-scope (L2-bypassing) access helpers ----------------
// Mutable cross-block state is accessed ONLY through these (sc1-flagged ops,
// coherent at the Infinity-Cache point) -> no wbl2/inv fences needed anywhere.
__device__ __forceinline__ float ld_devf(const float* p){
    return __hip_atomic_load(p, __ATOMIC_RELAXED, __HIP_MEMORY_SCOPE_AGENT);
}
__device__ __forceinline__ void st_devf(float* p, float v){
    __hip_atomic_store(p, v, __ATOMIC_RELAXED, __HIP_MEMORY_SCOPE_AGENT);
}
__device__ __forceinline__ float2 ld_devf2(const float* p){
    unsigned long long u = __hip_atomic_load((const unsigned long long*)p,
                                             __ATOMIC_RELAXED, __HIP_MEMORY_SCOPE_AGENT);
    return __builtin_bit_cast(float2, u);
}

// ---------------- grid barrier (persistent kernels) ----------------
// Two-level flag barrier with FAN-OUT release (8 relay lines -> <=32 pollers
// per line instead of 255 on one). Monotonic epochs, never reset
// (graph-replay safe). No threadfence: data moves via device-scope ops;
// s_waitcnt vmcnt(0) + __syncthreads() drains stores before arrival.
__device__ __align__(128) unsigned long long g_arr[256][16];   // arrival, 128B/blk
__device__ __align__(128) unsigned long long g_relA[8][16];    // release relays

__device__ __forceinline__ unsigned long long ld_flag(const unsigned long long* p){
    return __hip_atomic_load(p, __ATOMIC_RELAXED, __HIP_MEMORY_SCOPE_AGENT);
}
__device__ __forceinline__ void st_flag(unsigned long long* p, unsigned long long v){
    __hip_atomic_store(p, v, __ATOMIC_RELAXED, __HIP_MEMORY_SCOPE_AGENT);
}

__device__ __forceinline__ void gsync(unsigned long long ep){
    asm volatile("s_waitcnt vmcnt(0)" ::: "memory");  // own wave's stores drained
    __syncthreads();                                   // all waves drained
    if (blockIdx.x == 0){
        int tid = threadIdx.x;
        if (tid > 0){   // thread t waits for block t's arrival flag (1 poller/line)
            while (ld_flag(&g_arr[tid][0]) < ep)
                __builtin_amdgcn_s_sleep(1);
        }
        __syncthreads();
        if (tid < 8) st_flag(&g_relA[tid][0], ep);     // fan-out release
    } else {
        if (threadIdx.x == 0){
            st_flag(&g_arr[blockIdx.x][0], ep);
            while (ld_flag(&g_relA[blockIdx.x & 7][0]) < ep)
                __builtin_amdgcn_s_sleep(1);
        }
        __syncthreads();
    }
    asm volatile("" ::: "memory");   // compiler barrier: no hoisting above the poll
}

// ---------------- utility ----------------
__global__ void k_zero(float* p, int n){
    int i = blockIdx.x*256 + threadIdx.x;
    if (i < n) p[i] = 0.f;
}

// f32 [rows][ldin] (first 512 cols) -> bf16 [rows][512]
__global__ void k_cvt(const float* __restrict__ in, short* __restrict__ out, int ldin){
    long idx = (long)blockIdx.x*256 + threadIdx.x;
    long r = idx >> 9; int c = idx & 511;
    out[idx] = f2bf(in[r*ldin + c]);
}

// token gather -> bf16 rows. mode 0: src flat-reshape; mode 1: tgt transpose
__global__ void k_gather_bf(const float* __restrict__ emb, const int* __restrict__ tok,
                            short* __restrict__ out, int mode){
    long idx = (long)blockIdx.x*256 + threadIdx.x;   // 2048*512
    int m = idx >> 9, e = idx & 511;
    int ti = mode ? ((m & 31)*64 + (m >> 5)) : m;
    out[idx] = f2bf(emb[(long)tok[ti]*512 + e]);
}

// ---------------- MFMA bf16 GEMM: C[m,n] = sum_k A[m,k]*B[n,k], K=512 ----------------
// STORE=1: store f32 C (ldc=N). STORE=0: atomicAdd(sumexp[m], sum_n exp(C[m,n])).
template<int STORE>
__global__ __launch_bounds__(256)
void k_mfma_gemm(const short* __restrict__ A, const short* __restrict__ B,
                 float* __restrict__ C, int ldc){
    __shared__ short As[128][72];
    __shared__ short Bs[128][72];
    int tid = threadIdx.x, l = tid & 63, w = tid >> 6;
    int wm = w >> 1, wn = w & 1;
    long m0 = (long)blockIdx.x * 128, n0 = (long)blockIdx.y * 128;
    float4v acc[4][4];
    #pragma unroll
    for (int a=0;a<4;++a)
        #pragma unroll
        for (int b=0;b<4;++b)
            #pragma unroll
            for (int e=0;e<4;++e) acc[a][b][e] = 0.f;

    for (int kb = 0; kb < 8; ++kb){
        #pragma unroll
        for (int i = tid; i < 1024; i += 256){
            int r = i >> 3, c = i & 7;
            *(uint4*)&As[r][c*8] = *(const uint4*)(A + (m0+r)*512 + kb*64 + c*8);
            *(uint4*)&Bs[r][c*8] = *(const uint4*)(B + (n0+r)*512 + kb*64 + c*8);
        }
        __syncthreads();
        #pragma unroll
        for (int ks = 0; ks < 2; ++ks){
            short8 af[4], bf[4];
            #pragma unroll
            for (int tm=0;tm<4;++tm)
                af[tm] = *(const short8*)&As[wm*64 + tm*16 + (l&15)][ks*32 + (l>>4)*8];
            #pragma unroll
            for (int tn=0;tn<4;++tn)
                bf[tn] = *(const short8*)&Bs[wn*64 + tn*16 + (l&15)][ks*32 + (l>>4)*8];
            #pragma unroll
            for (int tm=0;tm<4;++tm)
                #pragma unroll
                for (int tn=0;tn<4;++tn)
                    acc[tm][tn] = __builtin_amdgcn_mfma_f32_16x16x32_bf16(
                        af[tm], bf[tn], acc[tm][tn], 0, 0, 0);
        }
        __syncthreads();
    }

    int q = l >> 4;  // quad group
    if (STORE){
        #pragma unroll
        for (int tm=0;tm<4;++tm)
            #pragma unroll
            for (int r=0;r<4;++r){
                long m = m0 + wm*64 + tm*16 + q*4 + r;
                #pragma unroll
                for (int tn=0;tn<4;++tn)
                    C[m*ldc + n0 + wn*64 + tn*16 + (l&15)] = acc[tm][tn][r];
            }
    } else {
        #pragma unroll
        for (int tm=0;tm<4;++tm)
            #pragma unroll
            for (int r=0;r<4;++r){
                float s = 0.f;
                #pragma unroll
                for (int tn=0;tn<4;++tn) s += __expf(acc[tm][tn][r]);
                s += __shfl_xor(s, 1); s += __shfl_xor(s, 2);
                s += __shfl_xor(s, 4); s += __shfl_xor(s, 8);
                if ((l & 15) == 0)
                    atomicAdd(&C[m0 + wm*64 + tm*16 + q*4 + r], s);
            }
    }
}

// ---------------- persistent encoder ----------------
// 256 blocks x 256 threads, 1 block/CU. dir = bid>>7, j-group of 4.
// Whh slice LDS-resident across all 64 steps; c-state register-resident.
// h exchange via device-scope (sc1) ops; 1 grid-sync per step, no fences.
__global__ __launch_bounds__(256, 1)
void k_encoder(const float* __restrict__ WhhF, const float* __restrict__ WhhB,
               const float* __restrict__ bF, const float* __restrict__ bB,
               const int* __restrict__ lens,
               float* __restrict__ hF, float* __restrict__ cF,
               float* __restrict__ hB, float* __restrict__ cB,
               float* __restrict__ senc)
{
    __shared__ float WS[16][516];   // 16 gate-rows x 512 (pad 4)
    __shared__ float xS[32][516];   // h stage [32][512] (pad 4)
    __shared__ float gS[32][16];    // gate partial exchange

    const int bid = blockIdx.x, tid = threadIdx.x;
    const int dir = bid >> 7, jg = bid & 127;
    const int j0 = jg * 4;
    const float* Whh  = dir ? WhhB : WhhF;
    const float* bias = dir ? bB : bF;
    const float* X = g_X[dir];
    float* hPtr = dir ? hB : hF;

    // stage W once: row nn -> gate n = (nn>>2)*512 + j0 + (nn&3)
    for (int i = tid; i < 2048; i += 256){
        int nn = i >> 7, c4 = i & 127;
        int n = (nn >> 2)*512 + j0 + (nn & 3);
        *(float4*)&WS[nn][c4*4] = *(const float4*)(Whh + (long)n*512 + c4*4);
    }

    const int nn = tid & 15, b2 = tid >> 4;        // compute map: 2 outputs (b2, b2+16)
    const int cb = tid >> 2, cjj = tid & 3;        // cell map (tid<128)
    const int len_b = lens[cb & 31];
    float c_reg = 0.f, h_reg = 0.f;

    unsigned long long ep = ld_flag(&g_relA[0][0]);

    for (int s = 0; s < 64; ++s){
        if (s){
            ep++; gsync(ep);
            for (int i = tid; i < 8192; i += 256){   // stage h [32][512] (device-scope)
                float2 v = ld_devf2(hPtr + i*2);
                xS[i >> 8][(i & 255)*2]     = v.x;
                xS[i >> 8][(i & 255)*2 + 1] = v.y;
            }
        }
        __syncthreads();
        float p[4] = {0.f,0.f,0.f,0.f}, q[4] = {0.f,0.f,0.f,0.f};
        if (s){
            const float* wr = &WS[nn][0];
            const float* xa = &xS[b2][0];
            const float* xb = &xS[b2 + 16][0];
            #pragma unroll 2
            for (int k = 0; k < 512; k += 16){
                #pragma unroll
                for (int u = 0; u < 4; ++u){
                    float4 w = *(const float4*)(wr + k + u*4);
                    float4 a = *(const float4*)(xa + k + u*4);
                    float4 b = *(const float4*)(xb + k + u*4);
                    p[u] += w.x*a.x + w.y*a.y + w.z*a.z + w.w*a.w;
                    q[u] += w.x*b.x + w.y*b.y + w.z*b.z + w.w*b.w;
                }
            }
        }
        gS[b2][nn]    = p[0]+p[1]+p[2]+p[3];
        gS[b2+16][nn] = q[0]+q[1]+q[2]+q[3];
        __syncthreads();
        if (tid < 128){
            int sd = dir ? 63 - s : s;
            int j = j0 + cjj;
            const float* xr = X + ((long)(sd*32 + cb))*2048;
            float g0 = gS[cb][cjj]      + xr[j]      + bias[j];
            float g1 = gS[cb][4 + cjj]  + xr[512+j]  + bias[512+j];
            float g2 = gS[cb][8 + cjj]  + xr[1024+j] + bias[1024+j];
            float g3 = gS[cb][12 + cjj] + xr[1536+j] + bias[1536+j];
            float cn = sigf(g1)*c_reg + sigf(g0)*tanhf(g2);
            float hn = sigf(g3)*tanhf(cn);
            bool valid = sd < len_b;
            c_reg = valid ? cn : c_reg;
            h_reg = valid ? hn : h_reg;
            st_devf(hPtr + cb*512 + j, h_reg);
            senc[((long)(cb*64 + sd))*1024 + dir*512 + j] = valid ? hn : 0.f;
        }
    }
    if (tid < 128){
        float* cOut = dir ? cB : cF;
        cOut[cb*512 + j0 + cjj] = c_reg;
    }
}

// ---------------- persistent decoder ----------------
// 256 blocks x 256 threads, 1 block/CU. TWO grid-syncs per step.
// Phase A: gates (h-dot hoisted pre-barrier) + cell (register c).
// Phase C (merged B+C): each block owns (b=bid>>3, 64-n slice = (bid&7)*64):
//   own scores (satt from L2, 8x redundant) -> softmax -> att[n] =
//   tanh( Wv_h . h  +  sum_s alpha_s * sv[b,s,n] )   [sv precomputed GEMM]
// Mutable cross-block state (dech, attG) via device-scope ops only;
// read-only satt/sv/Wv/Yg stay plain cached (L2-resident).
__global__ __launch_bounds__(256, 1)
void k_decoder(const float* __restrict__ dWhh, const float* __restrict__ dWih,
               const float* __restrict__ db, const float* __restrict__ Wv,
               const float* __restrict__ satt, const float* __restrict__ sv,
               const int* __restrict__ lens,
               float* __restrict__ dech, const float* __restrict__ decc,
               float* __restrict__ attG, float* __restrict__ aves)
{
    __shared__ float xS[32][516];     // stage [32][512] (pad 4)
    __shared__ float WdS[8][1028];    // 8 gate-rows x [Whh(512) | Wih-att(512)]
    __shared__ float gS[32][8];
    // phase C scratch (disjoint from A's arrays)
    __shared__ float hS[512];
    __shared__ float scoreQ[64][5];
    __shared__ float hpQ[64][5];
    __shared__ float alphaS[64];
    __shared__ float svP[4][68];

    const int bid = blockIdx.x, tid = threadIdx.x;
    const float* Yg = g_X[2];

    {   // stage decoder gate weights once
        int j0 = bid*2;
        for (int i = tid; i < 2048; i += 256){
            int nn = i >> 8, c4 = i & 255;
            int n = (nn >> 1)*512 + j0 + (nn & 1);
            float4 v;
            if (c4 < 128) v = *(const float4*)(dWhh + (long)n*512  + c4*4);
            else          v = *(const float4*)(dWih + (long)n*1024 + 512 + (c4-128)*4);
            *(float4*)&WdS[nn][c4*4] = v;
        }
    }

    // cell state in registers (tid<64): b = tid>>1, j = bid*2 + (tid&1)
    float c_reg = 0.f;
    if (tid < 64) c_reg = decc[(tid>>1)*512 + bid*2 + (tid&1)];

    const int nnA = tid & 7, bA = tid >> 3;   // phase A map: 1 output/thread
    const int cb = bid >> 3, cn0 = (bid & 7) * 64;   // phase C ownership
    const int clen = lens[cb];

    unsigned long long ep = ld_flag(&g_relA[0][0]);

    for (int t = 0; t < 64; ++t){
        // ---------- pre-barrier: stage h(t-1) + h-part gate dot ----------
        // dech stable between cell(t-1) and cell(t); overlaps others' phase C.
        for (int i = tid; i < 8192; i += 256){
            float2 v = ld_devf2(dech + i*2);
            xS[i >> 8][(i & 255)*2]     = v.x;
            xS[i >> 8][(i & 255)*2 + 1] = v.y;
        }
        __syncthreads();
        float p[4] = {0.f,0.f,0.f,0.f};
        {
            const float* wr = &WdS[nnA][0];
            const float* xr = &xS[bA][0];
            #pragma unroll 2
            for (int k = 0; k < 512; k += 16){
                #pragma unroll
                for (int u = 0; u < 4; ++u){
                    float4 w = *(const float4*)(wr + k + u*4);
                    float4 a = *(const float4*)(xr + k + u*4);
                    p[u] += w.x*a.x + w.y*a.y + w.z*a.z + w.w*a.w;
                }
            }
        }

        if (t){
            ep++; gsync(ep);   // C(t-1) done: attG(t-1) ready
            for (int i = tid; i < 8192; i += 256){
                float2 v = ld_devf2(attG + i*2);
                xS[i >> 8][(i & 255)*2]     = v.x;
                xS[i >> 8][(i & 255)*2 + 1] = v.y;
            }
            __syncthreads();
            const float* wr = &WdS[nnA][512];
            const float* xr = &xS[bA][0];
            #pragma unroll 2
            for (int k = 0; k < 512; k += 16){
                #pragma unroll
                for (int u = 0; u < 4; ++u){
                    float4 w = *(const float4*)(wr + k + u*4);
                    float4 a = *(const float4*)(xr + k + u*4);
                    p[u] += w.x*a.x + w.y*a.y + w.z*a.z + w.w*a.w;
                }
            }
        }
        gS[bA][nnA] = p[0]+p[1]+p[2]+p[3];
        __syncthreads();
        if (tid < 64){
            int b = tid >> 1, jj = tid & 1, j = bid*2 + jj;
            const float* yr = Yg + ((long)t*32 + b)*2048;
            float g0 = gS[b][0 + jj] + yr[j]      + db[j];
            float g1 = gS[b][2 + jj] + yr[512+j]  + db[512+j];
            float g2 = gS[b][4 + jj] + yr[1024+j] + db[1024+j];
            float g3 = gS[b][6 + jj] + yr[1536+j] + db[1536+j];
            float cn = sigf(g1)*c_reg + sigf(g0)*tanhf(g2);
            float hn = sigf(g3)*tanhf(cn);
            c_reg = cn;
            st_devf(dech + b*512 + j, hn);
        }
        ep++; gsync(ep);   // h(t) ready

        // ---------- merged phase C: scores+softmax+attvec slice ----------
        {
            float2 v = ld_devf2(dech + cb*512 + tid*2);
            hS[tid*2] = v.x; hS[tid*2 + 1] = v.y;
        }
        __syncthreads();
        {   // scores (satt) + h-part of attvec (Wv), fused loop
            int rr = tid >> 2, q = tid & 3;
            const float* sar = satt + ((long)(cb*64 + rr))*512 + q*128;
            const float* wvr = Wv + (long)(cn0 + rr)*1536 + q*128;
            const float* hr  = hS + q*128;
            float us[4] = {0.f,0.f,0.f,0.f}, uw[4] = {0.f,0.f,0.f,0.f};
            #pragma unroll 2
            for (int k = 0; k < 128; k += 16){
                #pragma unroll
                for (int u = 0; u < 4; ++u){
                    float4 h = *(const float4*)(hr  + k + u*4);
                    float4 a = *(const float4*)(sar + k + u*4);
                    float4 w = *(const float4*)(wvr + k + u*4);
                    us[u] += a.x*h.x + a.y*h.y + a.z*h.z + a.w*h.w;
                    uw[u] += w.x*h.x + w.y*h.y + w.z*h.z + w.w*h.w;
                }
            }
            scoreQ[rr][q] = us[0]+us[1]+us[2]+us[3];
            hpQ[rr][q]    = uw[0]+uw[1]+uw[2]+uw[3];
        }
        __syncthreads();
        if (tid < 64){
            float sc = scoreQ[tid][0]+scoreQ[tid][1]+scoreQ[tid][2]+scoreQ[tid][3];
            if (tid >= clen) sc = -INFINITY;
            float mx = sc;
            #pragma unroll
            for (int o=32;o>0;o>>=1) mx = fmaxf(mx, __shfl_xor(mx, o));
            float e = (sc == -INFINITY) ? 0.f : __expf(sc - mx);
            float sm = e;
            #pragma unroll
            for (int o=32;o>0;o>>=1) sm += __shfl_xor(sm, o);
            alphaS[tid] = e / fmaxf(sm, 1e-30f);
        }
        __syncthreads();
        {   // ctx-part via precomputed sv: sum_s alpha_s * sv[b,s,n]
            int n = tid & 63, part = tid >> 6;
            const float* svp = sv + ((long)(cb*64 + part*16))*512 + cn0 + n;
            float sp = 0.f;
            #pragma unroll
            for (int i2 = 0; i2 < 16; ++i2)
                sp += alphaS[part*16 + i2] * svp[(long)i2*512];
            svP[part][n] = sp;
        }
        __syncthreads();
        if (tid < 64){
            float val = hpQ[tid][0]+hpQ[tid][1]+hpQ[tid][2]+hpQ[tid][3]
                      + svP[0][tid]+svP[1][tid]+svP[2][tid]+svP[3][tid];
            float v = tanhf(val);
            st_devf(attG + cb*512 + cn0 + tid, v);
            long m = (long)t*32 + cb;
            aves[m*512 + cn0 + tid] = v;
            g_aves_bf[m*512 + cn0 + tid] = f2bf(v);
        }
        // attG stores drained by next gsync's vmcnt(0); stream order covers t=63.
    }
}

__global__ void k_ccat(const float* __restrict__ cF, const float* __restrict__ cB,
                       float* __restrict__ ccat){
    int idx = blockIdx.x*256 + threadIdx.x;   // 32*1024
    int b = idx >> 10, d = idx & 1023;
    ccat[idx] = (d < 512) ? cF[b*512+d] : cB[b*512+d-512];
}

// ---------------- generic f32 tiled GEMM (satt, init, sv) ----------------
__global__ __launch_bounds__(256)
void k_gemm(const float* __restrict__ A, const float* __restrict__ W,
            const float* __restrict__ bias, float* __restrict__ C,
            int M, int K, int lda, int ldw, int ldc){
    __shared__ float As[16][65];
    __shared__ float Wt[16][65];
    int tid = threadIdx.x;
    int m0 = blockIdx.x * 64, n0 = blockIdx.y * 64;
    int ty = tid >> 4, tx = tid & 15;
    int lm = tid >> 2, lk = (tid & 3) * 4;
    float acc[4][4] = {};
    for (int kt = 0; kt < K; kt += 16){
        float4 av;
        if (m0 + lm < M) av = *(const float4*)(A + (long)(m0+lm)*lda + kt + lk);
        else av = make_float4(0.f,0.f,0.f,0.f);
        As[lk+0][lm]=av.x; As[lk+1][lm]=av.y; As[lk+2][lm]=av.z; As[lk+3][lm]=av.w;
        float4 wv = *(const float4*)(W + (long)(n0+lm)*ldw + kt + lk);
        Wt[lk+0][lm]=wv.x; Wt[lk+1][lm]=wv.y; Wt[lk+2][lm]=wv.z; Wt[lk+3][lm]=wv.w;
        __syncthreads();
        #pragma unroll
        for (int k = 0; k < 16; ++k){
            float a0=As[k][ty*4+0], a1=As[k][ty*4+1], a2=As[k][ty*4+2], a3=As[k][ty*4+3];
            float b0=Wt[k][tx*4+0], b1=Wt[k][tx*4+1], b2=Wt[k][tx*4+2], b3=Wt[k][tx*4+3];
            acc[0][0]+=a0*b0; acc[0][1]+=a0*b1; acc[0][2]+=a0*b2; acc[0][3]+=a0*b3;
            acc[1][0]+=a1*b0; acc[1][1]+=a1*b1; acc[1][2]+=a1*b2; acc[1][3]+=a1*b3;
            acc[2][0]+=a2*b0; acc[2][1]+=a2*b1; acc[2][2]+=a2*b2; acc[2][3]+=a2*b3;
            acc[3][0]+=a3*b0; acc[3][1]+=a3*b1; acc[3][2]+=a3*b2; acc[3][3]+=a3*b3;
        }
        __syncthreads();
    }
    #pragma unroll
    for (int i=0;i<4;++i){
        int m = m0 + ty*4 + i;
        if (m >= M) continue;
        #pragma unroll
        for (int j=0;j<4;++j){
            int n = n0 + tx*4 + j;
            float v = acc[i][j];
            if (bias) v += bias[n];
            C[(long)m*ldc + n] = v;
        }
    }
}

__global__ void k_dec_init(const float* __restrict__ decc0, float* dech){
    int idx = blockIdx.x*256 + threadIdx.x;   // 16384
    dech[idx] = tanhf(decc0[idx]);
}

// ---------------- gold + final ----------------
__global__ void k_gold(const float* __restrict__ aves, const float* __restrict__ Wr,
                       const int* __restrict__ tgt, float* __restrict__ gold){
    int wid = threadIdx.x >> 6, lane = threadIdx.x & 63;
    int m = blockIdx.x*4 + wid;   // m = t*32 + b
    int t = m >> 5, b = m & 31;
    int g = tgt[b*64 + t];
    const float* arow = aves + (long)m*512;
    const float* wrow = Wr + (long)g*512;
    float p = 0.f;
    for (int k=lane; k<512; k+=64) p += arow[k]*wrow[k];
    #pragma unroll
    for (int o=32;o>0;o>>=1) p += __shfl_xor(p, o);
    if (lane == 0) gold[m] = p;
}

__global__ void k_final(const float* __restrict__ gold, const float* __restrict__ sumexp,
                        const int* __restrict__ tgt, float* __restrict__ out){
    int t = threadIdx.x;
    float a = 0.f;
    for (int b=0;b<32;++b){
        int m = t*32 + b;
        float lp = gold[m] - logf(fmaxf(sumexp[m], 1e-30f));
        if (tgt[b*64 + t] != 0) a += lp;
    }
    out[t] = a;
}

// ---------------- launch ----------------
extern "C" void kernel_launch(void* const* d_in, const int* in_sizes, int n_in,
                              void* d_out, int out_size, void* d_ws, size_t ws_size,
                              hipStream_t stream){
    const int* src_tok   = (const int*)d_in[0];
    const int* tgt_tok   = (const int*)d_in[1];
    const int* lens      = (const int*)d_in[2];
    const float* src_emb = (const float*)d_in[3];
    const float* tgt_emb = (const float*)d_in[4];
    const float* eWihF   = (const float*)d_in[5];
    const float* eWhhF   = (const float*)d_in[6];
    const float* ebF     = (const float*)d_in[7];
    const float* eWihB   = (const float*)d_in[8];
    const float* eWhhB   = (const float*)d_in[9];
    const float* ebB     = (const float*)d_in[10];
    const float* dWih    = (const float*)d_in[11];
    const float* dWhh    = (const float*)d_in[12];
    const float* db      = (const float*)d_in[13];
    const float* Wasrc   = (const float*)d_in[14];
    const float* Wavec   = (const float*)d_in[15];
    const float* Wread   = (const float*)d_in[16];
    const float* Winit   = (const float*)d_in[17];
    const float* binit   = (const float*)d_in[18];
    float* ws  = (float*)d_ws;
    float* out = (float*)d_out;

    float* senc = ws + o_senc;  float* satt = ws + o_satt; float* aves = ws + o_aves;
    float* hF = ws + o_hF; float* cF = ws + o_cF; float* hB = ws + o_hB; float* cB = ws + o_cB;
    float* sumexp = ws + o_sumexp; float* gold = ws + o_gold;
    float* ccat = ws + o_ccat;
    float* dech = ws + o_dech; float* decc = ws + o_decc;
    float* attG = ws + o_att; float* sv = ws + o_sv;

    // device-symbol pointers
    float* Xf; short *WreadBf, *srcxBf, *tgtyBf, *WihFbf, *WihBbf, *dWihYbf;
    hipGetSymbolAddress((void**)&Xf, HIP_SYMBOL(g_X));
    hipGetSymbolAddress((void**)&WreadBf, HIP_SYMBOL(g_Wread_bf));
    hipGetSymbolAddress((void**)&srcxBf, HIP_SYMBOL(g_bfA));
    hipGetSymbolAddress((void**)&WihFbf, HIP_SYMBOL(g_bfW));
    tgtyBf = srcxBf + 2048L*512;
    WihBbf = WihFbf + 2048L*512;
    dWihYbf = WihFbf + 2L*2048*512;

    // zero states + sumexp
    k_zero<<<264, 256, 0, stream>>>(hF, 67584);

    // bf16 conversions + gathers
    k_cvt<<<4096, 256, 0, stream>>>(eWihF, WihFbf, 512);
    k_cvt<<<4096, 256, 0, stream>>>(eWihB, WihBbf, 512);
    k_cvt<<<4096, 256, 0, stream>>>(dWih, dWihYbf, 1024);   // cols 0..511
    k_cvt<<<64000, 256, 0, stream>>>(Wread, WreadBf, 512);
    k_gather_bf<<<4096, 256, 0, stream>>>(src_emb, src_tok, srcxBf, 0);
    k_gather_bf<<<4096, 256, 0, stream>>>(tgt_emb, tgt_tok, tgtyBf, 1);

    // x-part precompute: Xf, Xb, Yg = emb x Wih^T (MFMA)
    k_mfma_gemm<1><<<dim3(16,16), 256, 0, stream>>>(srcxBf, WihFbf, Xf, 2048);
    k_mfma_gemm<1><<<dim3(16,16), 256, 0, stream>>>(srcxBf, WihBbf, Xf + 2048L*2048, 2048);
    k_mfma_gemm<1><<<dim3(16,16), 256, 0, stream>>>(tgtyBf, dWihYbf, Xf + 2L*2048*2048, 2048);

    // encoder recurrence: ONE persistent kernel (64 steps, 63 grid-syncs)
    k_encoder<<<256, 256, 0, stream>>>(eWhhF, eWhhB, ebF, ebB, lens, hF, cF, hB, cB, senc);

    // [c_f|c_b]; src_att; sv = senc . Wv_ctx^T (f32, exact-reassoc); decoder init
    k_ccat<<<128, 256, 0, stream>>>(cF, cB, ccat);
    k_gemm<<<dim3(32,8), 256, 0, stream>>>(senc, Wasrc, nullptr, satt, 2048, 1024, 1024, 1024, 512);
    k_gemm<<<dim3(32,8), 256, 0, stream>>>(senc, Wavec + 512, nullptr, sv, 2048, 1024, 1024, 1536, 512);
    k_gemm<<<dim3(1,8), 256, 0, stream>>>(ccat, Winit, binit, decc, 32, 1024, 1024, 1024, 512);
    k_dec_init<<<64, 256, 0, stream>>>(decc, dech);

    // decoder recurrence: ONE persistent kernel (64 steps, 127 grid-syncs)
    k_decoder<<<256, 256, 0, stream>>>(dWhh, dWih, db, Wavec, satt, sv, lens,
                                       dech, decc, attG, aves);

    // readout: MFMA bf16 GEMM with fused exp-sum; gold; final
    short* avesBf; hipGetSymbolAddress((void**)&avesBf, HIP_SYMBOL(g_aves_bf));
    k_mfma_gemm<0><<<dim3(16,250), 256, 0, stream>>>(avesBf, WreadBf, sumexp, 0);
    k_gold<<<512, 256, 0, stream>>>(aves, Wread, tgt_tok, gold);
    k_final<<<1, 64, 0, stream>>>(gold, sumexp, tgt_tok, out);
}